// Round 4
// baseline (405.542 us; speedup 1.0000x reference)
//
#include <hip/hip_runtime.h>
#include <stdint.h>

#define BATCH 4
#define SEQL  16384
#define DIM   64
#define NST   16
#define TOK   (BATCH*SEQL)        /* 65536 tokens */
#define EL    ((size_t)TOK*DIM)   /* 4194304 elems per [B,L,D] array */
#define NCH   512                 /* chunks per (b,dir) */
#define CHL   32                  /* chunk length; NCH*CHL == SEQL */

typedef __attribute__((ext_vector_type(8))) short short8;
typedef __attribute__((ext_vector_type(4))) float f32x4;

__device__ __forceinline__ float nan2num(float x, float nv, float pv, float mv){
  if (__builtin_isnan(x)) return nv;
  if (__builtin_isinf(x)) return x > 0.f ? pv : mv;
  return x;
}
__device__ __forceinline__ float siluf(float x){ return x / (1.f + __expf(-x)); }
__device__ __forceinline__ float b2f(unsigned short s){
  union { unsigned u; float f; } v; v.u = ((unsigned)s) << 16; return v.f;
}
__device__ __forceinline__ unsigned short f2b(float f){
  union { float f; unsigned u; } v; v.f = f;
  unsigned r = v.u + 0x7fffu + ((v.u >> 16) & 1u);   // RNE
  return (unsigned short)(r >> 16);
}

// ================================================================ MEGA1
__global__ __launch_bounds__(256) void mega1(
    const float* __restrict__ in0, const float* __restrict__ in1,
    const float* __restrict__ n0w, const float* __restrict__ n0b,
    const float* __restrict__ n1w, const float* __restrict__ n1b,
    const float* __restrict__ cww, const float* __restrict__ cwb,
    const float* __restrict__ cwnw, const float* __restrict__ cwnb,
    const float* __restrict__ ipw, const float* __restrict__ ipew,
    float* __restrict__ x0n, float* __restrict__ wg,
    float* __restrict__ xa,  float* __restrict__ xe,
    unsigned short* __restrict__ zb, unsigned short* __restrict__ zeb)
{
  __shared__ __align__(16) short Wl[192*72];
  __shared__ __align__(16) short Al[128*72];
  int tid = threadIdx.x;
  int t0 = blockIdx.x * 128;
  int lane = tid & 63, wv = tid >> 6;
  int n = lane & 15, q = lane >> 4;
  f32x4 wacc[2][4];

  #pragma unroll
  for (int s = 0; s < 2; ++s){
    const float* ips = s ? ipew : ipw;
    for (int sseg = tid; sseg < 192*8; sseg += 256){
      int row = sseg >> 3, sg = sseg & 7;
      const float* src = (row < 64) ? (cww + (size_t)row*128 + s*64 + sg*8)
                                    : (ips + (size_t)(row-64)*64 + sg*8);
      float4 f0 = ((const float4*)src)[0];
      float4 f1 = ((const float4*)src)[1];
      short8 v;
      v[0]=(short)f2b(f0.x); v[1]=(short)f2b(f0.y); v[2]=(short)f2b(f0.z); v[3]=(short)f2b(f0.w);
      v[4]=(short)f2b(f1.x); v[5]=(short)f2b(f1.y); v[6]=(short)f2b(f1.z); v[7]=(short)f2b(f1.w);
      *(short8*)&Wl[row*72 + sg*8] = v;
    }
    {
      const float* inp = s ? in1 : in0;
      const float* nw  = s ? n1w : n0w;
      const float* nb  = s ? n1b : n0b;
      int tl = tid >> 2, p = tid & 3;
      float gw[16], gb[16];
      #pragma unroll
      for (int i = 0; i < 4; ++i){
        float4 w4 = ((const float4*)(nw + p*16))[i];
        float4 b4 = ((const float4*)(nb + p*16))[i];
        gw[4*i]=w4.x; gw[4*i+1]=w4.y; gw[4*i+2]=w4.z; gw[4*i+3]=w4.w;
        gb[4*i]=b4.x; gb[4*i+1]=b4.y; gb[4*i+2]=b4.z; gb[4*i+3]=b4.w;
      }
      #pragma unroll
      for (int sp = 0; sp < 2; ++sp){
        int tok_l = sp*64 + tl;
        size_t ga = ((size_t)(t0 + tok_l))*64 + p*16;
        float v[16]; float s1 = 0.f, s2 = 0.f;
        #pragma unroll
        for (int i = 0; i < 4; ++i){
          float4 f = ((const float4*)(inp + ga))[i];
          float a0 = nan2num(f.x,0.f,1.f,-1.f), a1 = nan2num(f.y,0.f,1.f,-1.f);
          float a2 = nan2num(f.z,0.f,1.f,-1.f), a3 = nan2num(f.w,0.f,1.f,-1.f);
          v[4*i]=a0; v[4*i+1]=a1; v[4*i+2]=a2; v[4*i+3]=a3;
          s1 += a0+a1+a2+a3; s2 += a0*a0+a1*a1+a2*a2+a3*a3;
        }
        s1 += __shfl_xor(s1,1,64); s1 += __shfl_xor(s1,2,64);
        s2 += __shfl_xor(s2,1,64); s2 += __shfl_xor(s2,2,64);
        float m = s1*(1.f/64.f);
        float var = s2*(1.f/64.f) - m*m;
        float rs = rsqrtf(var + 1e-5f);
        float xr[16];
        #pragma unroll
        for (int i = 0; i < 16; ++i){
          float x = nan2num((v[i]-m)*rs*gw[i] + gb[i], 0.f, 1.f, -1.f);
          xr[i] = x;
          Al[tok_l*72 + p*16 + i] = (short)f2b(x);
        }
        if (s == 0){
          #pragma unroll
          for (int i = 0; i < 4; ++i)
            ((float4*)(x0n + ga))[i] = make_float4(xr[4*i],xr[4*i+1],xr[4*i+2],xr[4*i+3]);
        }
      }
    }
    __syncthreads();
    float* outx = s ? xe : xa;
    unsigned short* outz = s ? zeb : zb;
    #pragma unroll
    for (int mi = 0; mi < 2; ++mi){
      int mt = wv*2 + mi;
      short8 a0 = *(const short8*)&Al[(mt*16 + n)*72 + q*8];
      short8 a1 = *(const short8*)&Al[(mt*16 + n)*72 + 32 + q*8];
      #pragma unroll
      for (int o = 0; o < 12; ++o){
        short8 b0 = *(const short8*)&Wl[(o*16 + n)*72 + q*8];
        short8 b1 = *(const short8*)&Wl[(o*16 + n)*72 + 32 + q*8];
        f32x4 c = {0.f, 0.f, 0.f, 0.f};
        c = __builtin_amdgcn_mfma_f32_16x16x32_bf16(a0, b0, c, 0, 0, 0);
        c = __builtin_amdgcn_mfma_f32_16x16x32_bf16(a1, b1, c, 0, 0, 0);
        if (o < 4){
          if (s == 0) wacc[mi][o] = c; else wacc[mi][o] += c;
        } else if (o < 8){
          #pragma unroll
          for (int r = 0; r < 4; ++r)
            outx[((size_t)(t0 + mt*16 + q*4 + r))*64 + (o-4)*16 + n] = c[r];
        } else {
          #pragma unroll
          for (int r = 0; r < 4; ++r)
            outz[((size_t)(t0 + mt*16 + q*4 + r))*64 + (o-8)*16 + n] = f2b(c[r]);
        }
      }
    }
    if (s == 0) __syncthreads();
  }
  float cb_l[4], gnw[4], gnb[4];
  #pragma unroll
  for (int o = 0; o < 4; ++o){
    cb_l[o] = cwb[o*16+n]; gnw[o] = cwnw[o*16+n]; gnb[o] = cwnb[o*16+n];
  }
  #pragma unroll
  for (int mi = 0; mi < 2; ++mi){
    #pragma unroll
    for (int r = 0; r < 4; ++r){
      float v[4]; float sv = 0.f, sq = 0.f;
      #pragma unroll
      for (int o = 0; o < 4; ++o){
        v[o] = wacc[mi][o][r] + cb_l[o];
        sv += v[o]; sq += v[o]*v[o];
      }
      sv += __shfl_xor(sv,1,64); sv += __shfl_xor(sv,2,64);
      sv += __shfl_xor(sv,4,64); sv += __shfl_xor(sv,8,64);
      sq += __shfl_xor(sq,1,64); sq += __shfl_xor(sq,2,64);
      sq += __shfl_xor(sq,4,64); sq += __shfl_xor(sq,8,64);
      float m = sv*(1.f/64.f);
      float var = sq*(1.f/64.f) - m*m;
      float rs = rsqrtf(var + 1e-5f);
      size_t tok = (size_t)t0 + (wv*2+mi)*16 + q*4 + r;
      #pragma unroll
      for (int o = 0; o < 4; ++o){
        float wn = (v[o]-m)*rs*gnw[o] + gnb[o];
        wn = nan2num(wn, 0.5f, 1.f, 0.f);
        wn = 1.f/(1.f + __expf(-wn));
        wn = fminf(fmaxf(wn, 0.01f), 0.99f);
        wg[tok*64 + o*16 + n] = wn;
      }
    }
  }
}

// ================================================================ G2: conv + xproj
__global__ __launch_bounds__(256) void g2_convproj(
    const float* __restrict__ xa, const float* __restrict__ xe,
    const float* __restrict__ cwf, const float* __restrict__ cbf,
    const float* __restrict__ cwr, const float* __restrict__ cbr,
    const float* __restrict__ xpwf, const float* __restrict__ xpwr,
    float* __restrict__ uf, float* __restrict__ ur,
    float* __restrict__ dltf, float* __restrict__ dltr,
    float* __restrict__ Bf, float* __restrict__ Cf,
    float* __restrict__ Br, float* __restrict__ Cr)
{
  __shared__ __align__(16) short Wl[2*48*72];
  __shared__ __align__(16) short Al[2*128*72];
  int tid = threadIdx.x;
  int b = blockIdx.x >> 7, l0 = (blockIdx.x & 127) * 128;
  size_t base = (size_t)b * SEQL;
  for (int sseg = tid; sseg < 2*48*8; sseg += 256){
    int s = sseg >= 48*8;
    int rs = sseg - s*48*8;
    int row = rs >> 3, sg = rs & 7;
    const float* xp = s ? xpwr : xpwf;
    short8 v = {0,0,0,0,0,0,0,0};
    int srcrow = (row < 32) ? (4+row) : (row < 36) ? (row-32) : -1;
    if (srcrow >= 0){
      const float* src = xp + (size_t)srcrow*64 + sg*8;
      float4 f0 = ((const float4*)src)[0];
      float4 f1 = ((const float4*)src)[1];
      v[0]=(short)f2b(f0.x); v[1]=(short)f2b(f0.y); v[2]=(short)f2b(f0.z); v[3]=(short)f2b(f0.w);
      v[4]=(short)f2b(f1.x); v[5]=(short)f2b(f1.y); v[6]=(short)f2b(f1.z); v[7]=(short)f2b(f1.w);
    }
    *(short8*)&Wl[(s*48+row)*72 + sg*8] = v;
  }
  {
    int d = tid & 63, lq = tid >> 6;
    float4 wf4 = ((const float4*)cwf)[d];
    float4 wr4 = ((const float4*)cwr)[d];
    float bf = cbf[d], brr = cbr[d];
    for (int i = 0; i < 8; ++i){
      int ll = i*16 + lq*4;
      int gl = l0 + ll;
      float rv[7], sv[7];
      #pragma unroll
      for (int j = 0; j < 7; ++j){
        int li = gl - 3 + j;
        rv[j] = (li >= 0) ? xa[(base + li)*64 + d] : 0.f;
        int lj = gl + j;
        sv[j] = (lj < SEQL) ? xe[(base + lj)*64 + d] : 0.f;
      }
      #pragma unroll
      for (int k = 0; k < 4; ++k){
        float a = bf + wf4.x*rv[k] + wf4.y*rv[k+1] + wf4.z*rv[k+2] + wf4.w*rv[k+3];
        a = siluf(a);
        uf[(base + gl + k)*64 + d] = a;
        Al[(ll+k)*72 + d] = (short)f2b(a);
        float r = brr + wr4.w*sv[k] + wr4.z*sv[k+1] + wr4.y*sv[k+2] + wr4.x*sv[k+3];
        r = siluf(r);
        ur[(base + gl + k)*64 + d] = r;
        Al[(128 + ll + k)*72 + d] = (short)f2b(r);
      }
    }
  }
  __syncthreads();
  int lane = tid & 63, wv = tid >> 6;
  int n = lane & 15, q = lane >> 4;
  #pragma unroll
  for (int s = 0; s < 2; ++s){
    const short* As = &Al[s*128*72];
    const short* Ws = &Wl[s*48*72];
    float* Bo = s ? Br : Bf;
    float* Co = s ? Cr : Cf;
    float* Do = s ? dltr : dltf;
    #pragma unroll
    for (int mi = 0; mi < 2; ++mi){
      int mt = wv*2 + mi;
      short8 a0 = *(const short8*)&As[(mt*16 + n)*72 + q*8];
      short8 a1 = *(const short8*)&As[(mt*16 + n)*72 + 32 + q*8];
      f32x4 acc[3];
      #pragma unroll
      for (int o = 0; o < 3; ++o){
        short8 b0 = *(const short8*)&Ws[(o*16 + n)*72 + q*8];
        short8 b1 = *(const short8*)&Ws[(o*16 + n)*72 + 32 + q*8];
        f32x4 c = {0.f, 0.f, 0.f, 0.f};
        c = __builtin_amdgcn_mfma_f32_16x16x32_bf16(a0, b0, c, 0, 0, 0);
        c = __builtin_amdgcn_mfma_f32_16x16x32_bf16(a1, b1, c, 0, 0, 0);
        acc[o] = c;
      }
      #pragma unroll
      for (int r = 0; r < 4; ++r){
        size_t tok = base + l0 + mt*16 + q*4 + r;
        Bo[tok*16 + n] = acc[0][r];
        Co[tok*16 + n] = acc[1][r];
        if (n < 4) Do[tok*4 + n] = acc[2][r];
      }
    }
  }
}

__device__ __forceinline__ float softplusf(float x){
  return x > 20.f ? x : log1pf(__expf(x));
}

// ================================================================ K4a: chunk compose
// thread per (b,dir,d,chunk); explicit next-iter prefetch; exp2-folded A.
__global__ __launch_bounds__(256, 4) void k4a_scanA(
    const float* __restrict__ dltf, const float* __restrict__ dltr,
    const float* __restrict__ dtwf, const float* __restrict__ dtbf,
    const float* __restrict__ dtwr, const float* __restrict__ dtbr,
    const float* __restrict__ uf,  const float* __restrict__ ur,
    const float* __restrict__ Bf,  const float* __restrict__ Br,
    const float* __restrict__ Alf, const float* __restrict__ Alr,
    float* __restrict__ P, float* __restrict__ S)
{
  int g = blockIdx.x*256 + threadIdx.x;     // 262144 threads
  int d = g & 63, c = (g >> 6) & (NCH-1), dir = (g >> 15) & 1, b = g >> 16;
  const float* dlt = dir ? dltr : dltf;
  const float* u  = dir ? ur  : uf;
  const float* Bm = dir ? Br  : Bf;
  const float* Al = dir ? Alr : Alf;
  float4 wd = ((const float4*)(dir ? dtwr : dtwf))[d];
  float bd = (dir ? dtbr : dtbf)[d];
  float A2[16], Pp[16], Ss[16];
  #pragma unroll
  for (int n = 0; n < 16; n++){
    A2[n] = -__expf(Al[d*16+n]) * 1.44269504f;
    Pp[n] = 1.f; Ss[n] = 0.f;
  }
  size_t base = (size_t)b*SEQL;
  int stp = dir ? -1 : 1;
  size_t tok = base + (dir ? (SEQL-1 - c*CHL) : (c*CHL));
  float4 dl = *(const float4*)(dlt + tok*4);
  float uvv = u[tok*64 + d];
  const float4* B4 = (const float4*)(Bm + tok*16);
  float4 q0 = B4[0], q1 = B4[1], q2 = B4[2], q3 = B4[3];
  #pragma unroll 2
  for (int i = 0; i < CHL; i++){
    float4 dc = dl; float uc = uvv;
    float4 p0 = q0, p1 = q1, p2 = q2, p3 = q3;
    if (i + 1 < CHL){
      tok += stp;
      dl = *(const float4*)(dlt + tok*4);
      uvv = u[tok*64 + d];
      const float4* Bn = (const float4*)(Bm + tok*16);
      q0 = Bn[0]; q1 = Bn[1]; q2 = Bn[2]; q3 = Bn[3];
    }
    float dtv = softplusf(wd.x*dc.x + wd.y*dc.y + wd.z*dc.z + wd.w*dc.w + bd);
    float du = dtv * uc;
    float bb[16] = {p0.x,p0.y,p0.z,p0.w, p1.x,p1.y,p1.z,p1.w,
                    p2.x,p2.y,p2.z,p2.w, p3.x,p3.y,p3.z,p3.w};
    #pragma unroll
    for (int n = 0; n < 16; n++){
      float a = exp2f(dtv*A2[n]);
      Pp[n] *= a;
      Ss[n] = fmaf(a, Ss[n], du*bb[n]);
    }
  }
  float4* P4 = (float4*)P; float4* S4 = (float4*)S;
  #pragma unroll
  for (int k = 0; k < 4; k++){
    P4[(size_t)g*4+k] = make_float4(Pp[4*k], Pp[4*k+1], Pp[4*k+2], Pp[4*k+3]);
    S4[(size_t)g*4+k] = make_float4(Ss[4*k], Ss[4*k+1], Ss[4*k+2], Ss[4*k+3]);
  }
}

// ================================================================ K4b: Kogge-Stone carry scan
// block per (b,dir,d) = 512 blocks; thread t holds chunks 2t, 2t+1.
__global__ __launch_bounds__(256) void k4b_ks(float* __restrict__ P,
                                              const float* __restrict__ S)
{
  __shared__ float Pl[256*18], Sl[256*18];
  int t = threadIdx.x;
  int d = blockIdx.x & 63, bd = blockIdx.x >> 6;
  size_t i0 = (((size_t)bd*NCH + 2*t  )*64 + d)*16;
  size_t i1 = (((size_t)bd*NCH + 2*t+1)*64 + d)*16;
  float p0[16], s0[16], p[16], s[16];
  #pragma unroll
  for (int k = 0; k < 4; k++){
    float4 pv = ((const float4*)(P + i0))[k];
    float4 sv = ((const float4*)(S + i0))[k];
    p0[4*k]=pv.x; p0[4*k+1]=pv.y; p0[4*k+2]=pv.z; p0[4*k+3]=pv.w;
    s0[4*k]=sv.x; s0[4*k+1]=sv.y; s0[4*k+2]=sv.z; s0[4*k+3]=sv.w;
  }
  #pragma unroll
  for (int k = 0; k < 4; k++){
    float4 pv = ((const float4*)(P + i1))[k];
    float4 sv = ((const float4*)(S + i1))[k];
    p[4*k]=pv.x; p[4*k+1]=pv.y; p[4*k+2]=pv.z; p[4*k+3]=pv.w;
    s[4*k]=sv.x; s[4*k+1]=sv.y; s[4*k+2]=sv.z; s[4*k+3]=sv.w;
  }
  // pair combine into (p,s): chunk 2t then 2t+1
  #pragma unroll
  for (int n = 0; n < 16; n++){
    s[n] = fmaf(p[n], s0[n], s[n]);
    p[n] *= p0[n];
  }
  #pragma unroll
  for (int j = 0; j < 8; j++){
    *(float2*)&Pl[t*18 + 2*j] = make_float2(p[2*j], p[2*j+1]);
    *(float2*)&Sl[t*18 + 2*j] = make_float2(s[2*j], s[2*j+1]);
  }
  for (int step = 1; step < 256; step <<= 1){
    __syncthreads();
    float pp[16], ss[16];
    bool act = (t >= step);
    if (act){
      #pragma unroll
      for (int j = 0; j < 8; j++){
        float2 tp = *(const float2*)&Pl[(t-step)*18 + 2*j];
        float2 ts = *(const float2*)&Sl[(t-step)*18 + 2*j];
        pp[2*j]=tp.x; pp[2*j+1]=tp.y; ss[2*j]=ts.x; ss[2*j+1]=ts.y;
      }
    }
    __syncthreads();
    if (act){
      #pragma unroll
      for (int n = 0; n < 16; n++){
        s[n] = fmaf(p[n], ss[n], s[n]);
        p[n] *= pp[n];
      }
      #pragma unroll
      for (int j = 0; j < 8; j++){
        *(float2*)&Pl[t*18 + 2*j] = make_float2(p[2*j], p[2*j+1]);
        *(float2*)&Sl[t*18 + 2*j] = make_float2(s[2*j], s[2*j+1]);
      }
    }
  }
  __syncthreads();
  float h0[16];
  if (t == 0){
    #pragma unroll
    for (int n = 0; n < 16; n++) h0[n] = 0.f;
  } else {
    #pragma unroll
    for (int j = 0; j < 8; j++){
      float2 ts = *(const float2*)&Sl[(t-1)*18 + 2*j];
      h0[2*j]=ts.x; h0[2*j+1]=ts.y;
    }
  }
  // H_pre[2t] = h0; H_pre[2t+1] = p0*h0 + s0
  float h1[16];
  #pragma unroll
  for (int n = 0; n < 16; n++) h1[n] = fmaf(p0[n], h0[n], s0[n]);
  #pragma unroll
  for (int k = 0; k < 4; k++){
    ((float4*)(P + i0))[k] = make_float4(h0[4*k], h0[4*k+1], h0[4*k+2], h0[4*k+3]);
    ((float4*)(P + i1))[k] = make_float4(h1[4*k], h1[4*k+1], h1[4*k+2], h1[4*k+3]);
  }
}

// ================================================================ K4c: scan pass B
__global__ __launch_bounds__(256, 3) void k4c_scanB(
    const float* __restrict__ dltf, const float* __restrict__ dltr,
    const float* __restrict__ dtwf, const float* __restrict__ dtbf,
    const float* __restrict__ dtwr, const float* __restrict__ dtbr,
    const float* __restrict__ uf,  const float* __restrict__ ur,
    const float* __restrict__ Bf,  const float* __restrict__ Br,
    const float* __restrict__ Cf,  const float* __restrict__ Cr,
    const float* __restrict__ Alf, const float* __restrict__ Alr,
    const float* __restrict__ Dvf, const float* __restrict__ Dvr,
    const float* __restrict__ Hpre, float* __restrict__ yf, float* __restrict__ yr)
{
  int g = blockIdx.x*256 + threadIdx.x;
  int d = g & 63, c = (g >> 6) & (NCH-1), dir = (g >> 15) & 1, b = g >> 16;
  const float* dlt = dir ? dltr : dltf;
  const float* u  = dir ? ur  : uf;
  const float* Bm = dir ? Br  : Bf;
  const float* Cm = dir ? Cr  : Cf;
  const float* Al = dir ? Alr : Alf;
  float4 wd = ((const float4*)(dir ? dtwr : dtwf))[d];
  float bd = (dir ? dtbr : dtbf)[d];
  float Dd = (dir ? Dvr : Dvf)[d];
  float* y = dir ? yr : yf;
  float A2[16], h[16];
  const float4* H4 = (const float4*)Hpre;
  #pragma unroll
  for (int k = 0; k < 4; k++){
    float4 hv = H4[(size_t)g*4+k];
    h[4*k] = hv.x; h[4*k+1] = hv.y; h[4*k+2] = hv.z; h[4*k+3] = hv.w;
  }
  #pragma unroll
  for (int n = 0; n < 16; n++) A2[n] = -__expf(Al[d*16+n]) * 1.44269504f;
  size_t base = (size_t)b*SEQL;
  int stp = dir ? -1 : 1;
  size_t tok = base + (dir ? (SEQL-1 - c*CHL) : (c*CHL));
  float4 dl = *(const float4*)(dlt + tok*4);
  float uvv = u[tok*64 + d];
  const float4* B4 = (const float4*)(Bm + tok*16);
  const float4* C4 = (const float4*)(Cm + tok*16);
  float4 qb0 = B4[0], qb1 = B4[1], qb2 = B4[2], qb3 = B4[3];
  float4 qc0 = C4[0], qc1 = C4[1], qc2 = C4[2], qc3 = C4[3];
  #pragma unroll 2
  for (int i = 0; i < CHL; i++){
    float4 dc = dl; float uc = uvv;
    float4 pb0 = qb0, pb1 = qb1, pb2 = qb2, pb3 = qb3;
    float4 pc0 = qc0, pc1 = qc1, pc2 = qc2, pc3 = qc3;
    size_t tok_c = tok;
    if (i + 1 < CHL){
      tok += stp;
      dl = *(const float4*)(dlt + tok*4);
      uvv = u[tok*64 + d];
      const float4* Bn = (const float4*)(Bm + tok*16);
      const float4* Cn = (const float4*)(Cm + tok*16);
      qb0 = Bn[0]; qb1 = Bn[1]; qb2 = Bn[2]; qb3 = Bn[3];
      qc0 = Cn[0]; qc1 = Cn[1]; qc2 = Cn[2]; qc3 = Cn[3];
    }
    float dtv = softplusf(wd.x*dc.x + wd.y*dc.y + wd.z*dc.z + wd.w*dc.w + bd);
    float du = dtv*uc;
    float bb[16] = {pb0.x,pb0.y,pb0.z,pb0.w, pb1.x,pb1.y,pb1.z,pb1.w,
                    pb2.x,pb2.y,pb2.z,pb2.w, pb3.x,pb3.y,pb3.z,pb3.w};
    float cc[16] = {pc0.x,pc0.y,pc0.z,pc0.w, pc1.x,pc1.y,pc1.z,pc1.w,
                    pc2.x,pc2.y,pc2.z,pc2.w, pc3.x,pc3.y,pc3.z,pc3.w};
    float yv = uc*Dd;
    #pragma unroll
    for (int n = 0; n < 16; n++){
      float a = exp2f(dtv*A2[n]);
      h[n] = fmaf(a, h[n], du*bb[n]);
      yv = fmaf(h[n], cc[n], yv);
    }
    y[tok_c*64 + d] = yv;
  }
}

// ================================================================ G3: epilogue
__global__ __launch_bounds__(256) void g3_post(
    const float* __restrict__ yf, const float* __restrict__ yr,
    const unsigned short* __restrict__ zb, const unsigned short* __restrict__ zeb,
    const float* __restrict__ wg, const float* __restrict__ x0n,
    const float* __restrict__ in0,
    const float* __restrict__ mnw, const float* __restrict__ opw,
    const float* __restrict__ pnw, const float* __restrict__ pnb,
    float* __restrict__ out)
{
  __shared__ __align__(16) short Wl[64*72];
  __shared__ __align__(16) short Al[64*72];
  __shared__ float Dbuf[64*66];
  int tid = threadIdx.x;
  int t0 = blockIdx.x * 64;
  for (int sseg = tid; sseg < 64*8; sseg += 256){
    int row = sseg >> 3, sg = sseg & 7;
    const float* src = opw + (size_t)row*64 + sg*8;
    float4 f0 = ((const float4*)src)[0];
    float4 f1 = ((const float4*)src)[1];
    short8 v;
    v[0]=(short)f2b(f0.x); v[1]=(short)f2b(f0.y); v[2]=(short)f2b(f0.z); v[3]=(short)f2b(f0.w);
    v[4]=(short)f2b(f1.x); v[5]=(short)f2b(f1.y); v[6]=(short)f2b(f1.z); v[7]=(short)f2b(f1.w);
    *(short8*)&Wl[row*72 + sg*8] = v;
  }
  {
    int tl = tid >> 2, p = tid & 3;
    size_t g = (size_t)(t0 + tl)*64 + p*16;
    float4 yf4[4], yr4[4];
    #pragma unroll
    for (int i = 0; i < 4; i++){
      yf4[i] = ((const float4*)(yf + g))[i];
      yr4[i] = ((const float4*)(yr + g))[i];
    }
    short8 z8a  = *(const short8*)(zb + g);
    short8 z8b  = *(const short8*)(zb + g + 8);
    short8 ze8a = *(const short8*)(zeb + g);
    short8 ze8b = *(const short8*)(zeb + g + 8);
    float vy[16]; float ss = 0.f;
    #pragma unroll
    for (int i = 0; i < 16; i++){
      float yfv = ((const float*)yf4)[i];
      float yrv = ((const float*)yr4)[i];
      float zv  = b2f((unsigned short)(i < 8 ? z8a[i] : z8b[i-8]));
      float zev = b2f((unsigned short)(i < 8 ? ze8a[i] : ze8b[i-8]));
      float v = 0.5f*(yfv*siluf(zv) + yrv*siluf(zev));
      vy[i] = v; ss += v*v;
    }
    ss += __shfl_xor(ss, 1, 64);
    ss += __shfl_xor(ss, 2, 64);
    float rms = rsqrtf(ss*(1.f/64.f) + 1e-5f);
    #pragma unroll
    for (int i = 0; i < 16; i++){
      float w = mnw[p*16 + i];
      Al[tl*72 + p*16 + i] = (short)f2b(vy[i]*rms*w);
    }
  }
  __syncthreads();
  int lane = tid & 63, wv = tid >> 6;
  int n = lane & 15, q = lane >> 4;
  {
    short8 a0 = *(const short8*)&Al[(wv*16 + n)*72 + q*8];
    short8 a1 = *(const short8*)&Al[(wv*16 + n)*72 + 32 + q*8];
    #pragma unroll
    for (int o = 0; o < 4; ++o){
      short8 b0 = *(const short8*)&Wl[(o*16 + n)*72 + q*8];
      short8 b1 = *(const short8*)&Wl[(o*16 + n)*72 + 32 + q*8];
      f32x4 c = {0.f, 0.f, 0.f, 0.f};
      c = __builtin_amdgcn_mfma_f32_16x16x32_bf16(a0, b0, c, 0, 0, 0);
      c = __builtin_amdgcn_mfma_f32_16x16x32_bf16(a1, b1, c, 0, 0, 0);
      #pragma unroll
      for (int r = 0; r < 4; ++r)
        Dbuf[(wv*16 + q*4 + r)*66 + o*16 + n] = c[r];
    }
  }
  __syncthreads();
  float gpw = pnw[lane], gpb = pnb[lane];
  float s1, s2;
  for (int i = 0; i < 16; ++i){
    int tl = wv*16 + i;
    size_t off = (size_t)(t0 + tl)*64 + lane;
    float v = Dbuf[tl*66 + lane];
    s1 = v; s2 = v*v;
    #pragma unroll
    for (int o2 = 32; o2 > 0; o2 >>= 1){ s1 += __shfl_xor(s1,o2,64); s2 += __shfl_xor(s2,o2,64); }
    float m = s1*(1.f/64.f);
    float qv = s2*(1.f/64.f) - m*m;
    float o = (v-m)*rsqrtf(qv+1e-5f)*gpw + gpb;
    o = nan2num(o, 0.f, 1.f, -1.f);
    float w = wg[off];
    float skip = nan2num(in0[off], 0.f, 1.f, -1.f);
    out[off] = fmaf(o, w, fmaf(x0n[off], 1.f - w, skip));
  }
}

// ================================================================ launcher
extern "C" void kernel_launch(void* const* d_in, const int* in_sizes, int n_in,
                              void* d_out, int out_size, void* d_ws, size_t ws_size,
                              hipStream_t stream)
{
  (void)in_sizes; (void)n_in; (void)out_size; (void)ws_size;
  const float* in0  = (const float*)d_in[0];
  const float* in1  = (const float*)d_in[1];
  const float* n0w  = (const float*)d_in[2];
  const float* n0b  = (const float*)d_in[3];
  const float* n1w  = (const float*)d_in[4];
  const float* n1b  = (const float*)d_in[5];
  const float* cww  = (const float*)d_in[6];
  const float* cwb  = (const float*)d_in[7];
  const float* cwnw = (const float*)d_in[8];
  const float* cwnb = (const float*)d_in[9];
  const float* ipw  = (const float*)d_in[10];
  const float* ipew = (const float*)d_in[11];
  const float* cwf  = (const float*)d_in[12];
  const float* cbf  = (const float*)d_in[13];
  const float* xpwf = (const float*)d_in[14];
  const float* dtwf = (const float*)d_in[15];
  const float* dtbf = (const float*)d_in[16];
  const float* Alf  = (const float*)d_in[17];
  const float* Dvf  = (const float*)d_in[18];
  const float* cwr  = (const float*)d_in[19];
  const float* cbr  = (const float*)d_in[20];
  const float* xpwr = (const float*)d_in[21];
  const float* dtwr = (const float*)d_in[22];
  const float* dtbr = (const float*)d_in[23];
  const float* Alr  = (const float*)d_in[24];
  const float* Dvr  = (const float*)d_in[25];
  const float* mnw  = (const float*)d_in[26];
  const float* opw  = (const float*)d_in[27];
  const float* pnw  = (const float*)d_in[28];
  const float* pnb  = (const float*)d_in[29];

  float* ws  = (float*)d_ws;
  float* x0n = ws + 0*EL;
  float* xa  = ws + 1*EL;   // conv input fwd; reused as yf
  float* xe  = ws + 2*EL;   // conv input rev; reused as yr
  float* uf  = ws + 3*EL;
  float* ur  = ws + 4*EL;
  float* wg  = ws + 5*EL;
  float* Bf  = ws + 6*EL;              // TOK*16 each (4 arrays = EL total)
  float* Cf  = Bf + (size_t)TOK*16;
  float* Br  = Cf + (size_t)TOK*16;
  float* Cr  = Br + (size_t)TOK*16;
  float* P   = ws + 7*EL;              // 262144*16 floats = EL
  float* S   = ws + 8*EL;              // EL
  unsigned short* zb  = (unsigned short*)(ws + 9*EL);
  unsigned short* zeb = zb + EL;
  float* dltf = ws + 10*EL;            // TOK*4 each
  float* dltr = dltf + (size_t)TOK*4;
  float* yfp = xa;
  float* yrp = xe;

  mega1<<<512, 256, 0, stream>>>(in0, in1, n0w, n0b, n1w, n1b, cww, cwb,
                                 cwnw, cwnb, ipw, ipew,
                                 x0n, wg, xa, xe, zb, zeb);
  g2_convproj<<<512, 256, 0, stream>>>(xa, xe, cwf, cbf, cwr, cbr,
                                       xpwf, xpwr,
                                       uf, ur, dltf, dltr, Bf, Cf, Br, Cr);
  k4a_scanA<<<1024, 256, 0, stream>>>(dltf, dltr, dtwf, dtbf, dtwr, dtbr,
                                      uf, ur, Bf, Br, Alf, Alr, P, S);
  k4b_ks<<<512, 256, 0, stream>>>(P, S);
  k4c_scanB<<<1024, 256, 0, stream>>>(dltf, dltr, dtwf, dtbf, dtwr, dtbr,
                                      uf, ur, Bf, Br, Cf, Cr,
                                      Alf, Alr, Dvf, Dvr, P, yfp, yrp);
  g3_post<<<1024, 256, 0, stream>>>(yfp, yrp, zb, zeb, wg, x0n, in0,
                                    mnw, opw, pnw, pnb, (float*)d_out);
}

// Round 5
// 404.461 us; speedup vs baseline: 1.0027x; 1.0027x over previous
//
#include <hip/hip_runtime.h>
#include <stdint.h>

#define BATCH 4
#define SEQL  16384
#define DIM   64
#define NST   16
#define TOK   (BATCH*SEQL)        /* 65536 tokens */
#define EL    ((size_t)TOK*DIM)   /* 4194304 elems per [B,L,D] array */
#define NCH   256                 /* chunks per (b,dir) */
#define CHL   64                  /* chunk length; NCH*CHL == SEQL */

typedef __attribute__((ext_vector_type(8))) short short8;
typedef __attribute__((ext_vector_type(4))) float f32x4;

__device__ __forceinline__ float nan2num(float x, float nv, float pv, float mv){
  if (__builtin_isnan(x)) return nv;
  if (__builtin_isinf(x)) return x > 0.f ? pv : mv;
  return x;
}
__device__ __forceinline__ float siluf(float x){ return x / (1.f + __expf(-x)); }
__device__ __forceinline__ float b2f(unsigned short s){
  union { unsigned u; float f; } v; v.u = ((unsigned)s) << 16; return v.f;
}
__device__ __forceinline__ unsigned short f2b(float f){
  union { float f; unsigned u; } v; v.f = f;
  unsigned r = v.u + 0x7fffu + ((v.u >> 16) & 1u);   // RNE
  return (unsigned short)(r >> 16);
}
__device__ __forceinline__ float softplusf(float x){
  return x > 20.f ? x : log1pf(__expf(x));
}

// ================================================================ MEGA1
__global__ __launch_bounds__(256) void mega1(
    const float* __restrict__ in0, const float* __restrict__ in1,
    const float* __restrict__ n0w, const float* __restrict__ n0b,
    const float* __restrict__ n1w, const float* __restrict__ n1b,
    const float* __restrict__ cww, const float* __restrict__ cwb,
    const float* __restrict__ cwnw, const float* __restrict__ cwnb,
    const float* __restrict__ ipw, const float* __restrict__ ipew,
    float* __restrict__ x0n, float* __restrict__ wg,
    float* __restrict__ xa,  float* __restrict__ xe,
    unsigned short* __restrict__ zb, unsigned short* __restrict__ zeb)
{
  __shared__ __align__(16) short Wl[192*72];
  __shared__ __align__(16) short Al[128*72];
  int tid = threadIdx.x;
  int t0 = blockIdx.x * 128;
  int lane = tid & 63, wv = tid >> 6;
  int n = lane & 15, q = lane >> 4;
  f32x4 wacc[2][4];

  #pragma unroll
  for (int s = 0; s < 2; ++s){
    const float* ips = s ? ipew : ipw;
    for (int sseg = tid; sseg < 192*8; sseg += 256){
      int row = sseg >> 3, sg = sseg & 7;
      const float* src = (row < 64) ? (cww + (size_t)row*128 + s*64 + sg*8)
                                    : (ips + (size_t)(row-64)*64 + sg*8);
      float4 f0 = ((const float4*)src)[0];
      float4 f1 = ((const float4*)src)[1];
      short8 v;
      v[0]=(short)f2b(f0.x); v[1]=(short)f2b(f0.y); v[2]=(short)f2b(f0.z); v[3]=(short)f2b(f0.w);
      v[4]=(short)f2b(f1.x); v[5]=(short)f2b(f1.y); v[6]=(short)f2b(f1.z); v[7]=(short)f2b(f1.w);
      *(short8*)&Wl[row*72 + sg*8] = v;
    }
    {
      const float* inp = s ? in1 : in0;
      const float* nw  = s ? n1w : n0w;
      const float* nb  = s ? n1b : n0b;
      int tl = tid >> 2, p = tid & 3;
      float gw[16], gb[16];
      #pragma unroll
      for (int i = 0; i < 4; ++i){
        float4 w4 = ((const float4*)(nw + p*16))[i];
        float4 b4 = ((const float4*)(nb + p*16))[i];
        gw[4*i]=w4.x; gw[4*i+1]=w4.y; gw[4*i+2]=w4.z; gw[4*i+3]=w4.w;
        gb[4*i]=b4.x; gb[4*i+1]=b4.y; gb[4*i+2]=b4.z; gb[4*i+3]=b4.w;
      }
      #pragma unroll
      for (int sp = 0; sp < 2; ++sp){
        int tok_l = sp*64 + tl;
        size_t ga = ((size_t)(t0 + tok_l))*64 + p*16;
        float v[16]; float s1 = 0.f, s2 = 0.f;
        #pragma unroll
        for (int i = 0; i < 4; ++i){
          float4 f = ((const float4*)(inp + ga))[i];
          float a0 = nan2num(f.x,0.f,1.f,-1.f), a1 = nan2num(f.y,0.f,1.f,-1.f);
          float a2 = nan2num(f.z,0.f,1.f,-1.f), a3 = nan2num(f.w,0.f,1.f,-1.f);
          v[4*i]=a0; v[4*i+1]=a1; v[4*i+2]=a2; v[4*i+3]=a3;
          s1 += a0+a1+a2+a3; s2 += a0*a0+a1*a1+a2*a2+a3*a3;
        }
        s1 += __shfl_xor(s1,1,64); s1 += __shfl_xor(s1,2,64);
        s2 += __shfl_xor(s2,1,64); s2 += __shfl_xor(s2,2,64);
        float m = s1*(1.f/64.f);
        float var = s2*(1.f/64.f) - m*m;
        float rs = rsqrtf(var + 1e-5f);
        float xr[16];
        #pragma unroll
        for (int i = 0; i < 16; ++i){
          float x = nan2num((v[i]-m)*rs*gw[i] + gb[i], 0.f, 1.f, -1.f);
          xr[i] = x;
          Al[tok_l*72 + p*16 + i] = (short)f2b(x);
        }
        if (s == 0){
          #pragma unroll
          for (int i = 0; i < 4; ++i)
            ((float4*)(x0n + ga))[i] = make_float4(xr[4*i],xr[4*i+1],xr[4*i+2],xr[4*i+3]);
        }
      }
    }
    __syncthreads();
    float* outx = s ? xe : xa;
    unsigned short* outz = s ? zeb : zb;
    #pragma unroll
    for (int mi = 0; mi < 2; ++mi){
      int mt = wv*2 + mi;
      short8 a0 = *(const short8*)&Al[(mt*16 + n)*72 + q*8];
      short8 a1 = *(const short8*)&Al[(mt*16 + n)*72 + 32 + q*8];
      #pragma unroll
      for (int o = 0; o < 12; ++o){
        short8 b0 = *(const short8*)&Wl[(o*16 + n)*72 + q*8];
        short8 b1 = *(const short8*)&Wl[(o*16 + n)*72 + 32 + q*8];
        f32x4 c = {0.f, 0.f, 0.f, 0.f};
        c = __builtin_amdgcn_mfma_f32_16x16x32_bf16(a0, b0, c, 0, 0, 0);
        c = __builtin_amdgcn_mfma_f32_16x16x32_bf16(a1, b1, c, 0, 0, 0);
        if (o < 4){
          if (s == 0) wacc[mi][o] = c; else wacc[mi][o] += c;
        } else if (o < 8){
          #pragma unroll
          for (int r = 0; r < 4; ++r)
            outx[((size_t)(t0 + mt*16 + q*4 + r))*64 + (o-4)*16 + n] = c[r];
        } else {
          #pragma unroll
          for (int r = 0; r < 4; ++r)
            outz[((size_t)(t0 + mt*16 + q*4 + r))*64 + (o-8)*16 + n] = f2b(c[r]);
        }
      }
    }
    if (s == 0) __syncthreads();
  }
  float cb_l[4], gnw[4], gnb[4];
  #pragma unroll
  for (int o = 0; o < 4; ++o){
    cb_l[o] = cwb[o*16+n]; gnw[o] = cwnw[o*16+n]; gnb[o] = cwnb[o*16+n];
  }
  #pragma unroll
  for (int mi = 0; mi < 2; ++mi){
    #pragma unroll
    for (int r = 0; r < 4; ++r){
      float v[4]; float sv = 0.f, sq = 0.f;
      #pragma unroll
      for (int o = 0; o < 4; ++o){
        v[o] = wacc[mi][o][r] + cb_l[o];
        sv += v[o]; sq += v[o]*v[o];
      }
      sv += __shfl_xor(sv,1,64); sv += __shfl_xor(sv,2,64);
      sv += __shfl_xor(sv,4,64); sv += __shfl_xor(sv,8,64);
      sq += __shfl_xor(sq,1,64); sq += __shfl_xor(sq,2,64);
      sq += __shfl_xor(sq,4,64); sq += __shfl_xor(sq,8,64);
      float m = sv*(1.f/64.f);
      float var = sq*(1.f/64.f) - m*m;
      float rs = rsqrtf(var + 1e-5f);
      size_t tok = (size_t)t0 + (wv*2+mi)*16 + q*4 + r;
      #pragma unroll
      for (int o = 0; o < 4; ++o){
        float wn = (v[o]-m)*rs*gnw[o] + gnb[o];
        wn = nan2num(wn, 0.5f, 1.f, 0.f);
        wn = 1.f/(1.f + __expf(-wn));
        wn = fminf(fmaxf(wn, 0.01f), 0.99f);
        wg[tok*64 + o*16 + n] = wn;
      }
    }
  }
}

// ================================================================ G2: conv + xproj
__global__ __launch_bounds__(256) void g2_convproj(
    const float* __restrict__ xa, const float* __restrict__ xe,
    const float* __restrict__ cwf, const float* __restrict__ cbf,
    const float* __restrict__ cwr, const float* __restrict__ cbr,
    const float* __restrict__ xpwf, const float* __restrict__ xpwr,
    float* __restrict__ uf, float* __restrict__ ur,
    float* __restrict__ dltf, float* __restrict__ dltr,
    float* __restrict__ Bf, float* __restrict__ Cf,
    float* __restrict__ Br, float* __restrict__ Cr)
{
  __shared__ __align__(16) short Wl[2*48*72];
  __shared__ __align__(16) short Al[2*128*72];
  int tid = threadIdx.x;
  int b = blockIdx.x >> 7, l0 = (blockIdx.x & 127) * 128;
  size_t base = (size_t)b * SEQL;
  for (int sseg = tid; sseg < 2*48*8; sseg += 256){
    int s = sseg >= 48*8;
    int rs = sseg - s*48*8;
    int row = rs >> 3, sg = rs & 7;
    const float* xp = s ? xpwr : xpwf;
    short8 v = {0,0,0,0,0,0,0,0};
    int srcrow = (row < 32) ? (4+row) : (row < 36) ? (row-32) : -1;
    if (srcrow >= 0){
      const float* src = xp + (size_t)srcrow*64 + sg*8;
      float4 f0 = ((const float4*)src)[0];
      float4 f1 = ((const float4*)src)[1];
      v[0]=(short)f2b(f0.x); v[1]=(short)f2b(f0.y); v[2]=(short)f2b(f0.z); v[3]=(short)f2b(f0.w);
      v[4]=(short)f2b(f1.x); v[5]=(short)f2b(f1.y); v[6]=(short)f2b(f1.z); v[7]=(short)f2b(f1.w);
    }
    *(short8*)&Wl[(s*48+row)*72 + sg*8] = v;
  }
  {
    int d = tid & 63, lq = tid >> 6;
    float4 wf4 = ((const float4*)cwf)[d];
    float4 wr4 = ((const float4*)cwr)[d];
    float bf = cbf[d], brr = cbr[d];
    for (int i = 0; i < 8; ++i){
      int ll = i*16 + lq*4;
      int gl = l0 + ll;
      float rv[7], sv[7];
      #pragma unroll
      for (int j = 0; j < 7; ++j){
        int li = gl - 3 + j;
        rv[j] = (li >= 0) ? xa[(base + li)*64 + d] : 0.f;
        int lj = gl + j;
        sv[j] = (lj < SEQL) ? xe[(base + lj)*64 + d] : 0.f;
      }
      #pragma unroll
      for (int k = 0; k < 4; ++k){
        float a = bf + wf4.x*rv[k] + wf4.y*rv[k+1] + wf4.z*rv[k+2] + wf4.w*rv[k+3];
        a = siluf(a);
        uf[(base + gl + k)*64 + d] = a;
        Al[(ll+k)*72 + d] = (short)f2b(a);
        float r = brr + wr4.w*sv[k] + wr4.z*sv[k+1] + wr4.y*sv[k+2] + wr4.x*sv[k+3];
        r = siluf(r);
        ur[(base + gl + k)*64 + d] = r;
        Al[(128 + ll + k)*72 + d] = (short)f2b(r);
      }
    }
  }
  __syncthreads();
  int lane = tid & 63, wv = tid >> 6;
  int n = lane & 15, q = lane >> 4;
  #pragma unroll
  for (int s = 0; s < 2; ++s){
    const short* As = &Al[s*128*72];
    const short* Ws = &Wl[s*48*72];
    float* Bo = s ? Br : Bf;
    float* Co = s ? Cr : Cf;
    float* Do = s ? dltr : dltf;
    #pragma unroll
    for (int mi = 0; mi < 2; ++mi){
      int mt = wv*2 + mi;
      short8 a0 = *(const short8*)&As[(mt*16 + n)*72 + q*8];
      short8 a1 = *(const short8*)&As[(mt*16 + n)*72 + 32 + q*8];
      f32x4 acc[3];
      #pragma unroll
      for (int o = 0; o < 3; ++o){
        short8 b0 = *(const short8*)&Ws[(o*16 + n)*72 + q*8];
        short8 b1 = *(const short8*)&Ws[(o*16 + n)*72 + 32 + q*8];
        f32x4 c = {0.f, 0.f, 0.f, 0.f};
        c = __builtin_amdgcn_mfma_f32_16x16x32_bf16(a0, b0, c, 0, 0, 0);
        c = __builtin_amdgcn_mfma_f32_16x16x32_bf16(a1, b1, c, 0, 0, 0);
        acc[o] = c;
      }
      #pragma unroll
      for (int r = 0; r < 4; ++r){
        size_t tok = base + l0 + mt*16 + q*4 + r;
        Bo[tok*16 + n] = acc[0][r];
        Co[tok*16 + n] = acc[1][r];
        if (n < 4) Do[tok*4 + n] = acc[2][r];
      }
    }
  }
}

// ================================================================ K4a: chunk compose
// thread = (b,dir,chunk,d,n-half): 8 states each; lane = nh*32+dlo.
__global__ __launch_bounds__(256, 4) void k4a_scanA(
    const float* __restrict__ dltf, const float* __restrict__ dltr,
    const float* __restrict__ dtwf, const float* __restrict__ dtbf,
    const float* __restrict__ dtwr, const float* __restrict__ dtbr,
    const float* __restrict__ uf,  const float* __restrict__ ur,
    const float* __restrict__ Bf,  const float* __restrict__ Br,
    const float* __restrict__ Alf, const float* __restrict__ Alr,
    float* __restrict__ P, float* __restrict__ S)
{
  int g = blockIdx.x*256 + threadIdx.x;     // 262144 threads
  int lane = threadIdx.x & 63;
  int nh = lane >> 5, dlo = lane & 31;
  int dhi = (g >> 6) & 1;
  int d = dhi*32 + dlo;
  int c = (g >> 7) & (NCH-1);
  int dir = (g >> 15) & 1;
  int b = g >> 16;
  const float* dlt = dir ? dltr : dltf;
  const float* u  = dir ? ur  : uf;
  const float* Bm = dir ? Br  : Bf;
  const float* Al = dir ? Alr : Alf;
  float4 wd = ((const float4*)(dir ? dtwr : dtwf))[d];
  float bd = (dir ? dtbr : dtbf)[d];
  float A2[8], Pp[8], Ss[8];
  #pragma unroll
  for (int j = 0; j < 8; j++){
    A2[j] = -__expf(Al[d*16 + nh*8 + j]) * 1.44269504f;
    Pp[j] = 1.f; Ss[j] = 0.f;
  }
  size_t base = (size_t)b*SEQL;
  int stp = dir ? -1 : 1;
  size_t tok = base + (dir ? (SEQL-1 - c*CHL) : (c*CHL));
  float4 dl = *(const float4*)(dlt + tok*4);
  float uvv = u[tok*64 + d];
  const float4* B4 = (const float4*)(Bm + tok*16 + nh*8);
  float4 q0 = B4[0], q1 = B4[1];
  #pragma unroll 2
  for (int i = 0; i < CHL; i++){
    float4 dc = dl; float uc = uvv;
    float4 p0 = q0, p1 = q1;
    if (i + 1 < CHL){
      tok += stp;
      dl = *(const float4*)(dlt + tok*4);
      uvv = u[tok*64 + d];
      const float4* Bn = (const float4*)(Bm + tok*16 + nh*8);
      q0 = Bn[0]; q1 = Bn[1];
    }
    float dtv = softplusf(wd.x*dc.x + wd.y*dc.y + wd.z*dc.z + wd.w*dc.w + bd);
    float du = dtv * uc;
    float bb[8] = {p0.x,p0.y,p0.z,p0.w, p1.x,p1.y,p1.z,p1.w};
    #pragma unroll
    for (int j = 0; j < 8; j++){
      float a = exp2f(dtv*A2[j]);
      Pp[j] *= a;
      Ss[j] = fmaf(a, Ss[j], du*bb[j]);
    }
  }
  size_t pidx = (((size_t)(b*2+dir)*NCH + c)*64 + d)*16 + nh*8;
  ((float4*)(P+pidx))[0] = make_float4(Pp[0],Pp[1],Pp[2],Pp[3]);
  ((float4*)(P+pidx))[1] = make_float4(Pp[4],Pp[5],Pp[6],Pp[7]);
  ((float4*)(S+pidx))[0] = make_float4(Ss[0],Ss[1],Ss[2],Ss[3]);
  ((float4*)(S+pidx))[1] = make_float4(Ss[4],Ss[5],Ss[6],Ss[7]);
}

// ================================================================ K4b: Kogge-Stone carry scan
// block per (b,dir,d) = 512 blocks; thread c in [0,256) holds 16 (p,s) pairs.
__global__ __launch_bounds__(256) void k4b_ks(float* __restrict__ P,
                                              const float* __restrict__ S)
{
  __shared__ float Pl[256*18], Sl[256*18];
  int c = threadIdx.x;
  int d = blockIdx.x & 63, bd = blockIdx.x >> 6;
  size_t idx = (((size_t)bd*NCH + c)*64 + d)*16;
  float p[16], s[16];
  #pragma unroll
  for (int k = 0; k < 4; k++){
    float4 pv = ((const float4*)(P + idx))[k];
    float4 sv = ((const float4*)(S + idx))[k];
    p[4*k]=pv.x; p[4*k+1]=pv.y; p[4*k+2]=pv.z; p[4*k+3]=pv.w;
    s[4*k]=sv.x; s[4*k+1]=sv.y; s[4*k+2]=sv.z; s[4*k+3]=sv.w;
  }
  #pragma unroll
  for (int j = 0; j < 8; j++){
    *(float2*)&Pl[c*18 + 2*j] = make_float2(p[2*j], p[2*j+1]);
    *(float2*)&Sl[c*18 + 2*j] = make_float2(s[2*j], s[2*j+1]);
  }
  for (int step = 1; step < NCH; step <<= 1){
    __syncthreads();
    float pp[16], ss[16];
    bool act = (c >= step);
    if (act){
      #pragma unroll
      for (int j = 0; j < 8; j++){
        float2 tp = *(const float2*)&Pl[(c-step)*18 + 2*j];
        float2 ts = *(const float2*)&Sl[(c-step)*18 + 2*j];
        pp[2*j]=tp.x; pp[2*j+1]=tp.y; ss[2*j]=ts.x; ss[2*j+1]=ts.y;
      }
    }
    __syncthreads();
    if (act){
      #pragma unroll
      for (int n = 0; n < 16; n++){
        s[n] = fmaf(p[n], ss[n], s[n]);
        p[n] *= pp[n];
      }
      #pragma unroll
      for (int j = 0; j < 8; j++){
        *(float2*)&Pl[c*18 + 2*j] = make_float2(p[2*j], p[2*j+1]);
        *(float2*)&Sl[c*18 + 2*j] = make_float2(s[2*j], s[2*j+1]);
      }
    }
  }
  __syncthreads();
  float ho[16];
  if (c == 0){
    #pragma unroll
    for (int n = 0; n < 16; n++) ho[n] = 0.f;
  } else {
    #pragma unroll
    for (int j = 0; j < 8; j++){
      float2 ts = *(const float2*)&Sl[(c-1)*18 + 2*j];
      ho[2*j]=ts.x; ho[2*j+1]=ts.y;
    }
  }
  #pragma unroll
  for (int k = 0; k < 4; k++)
    ((float4*)(P + idx))[k] = make_float4(ho[4*k], ho[4*k+1], ho[4*k+2], ho[4*k+3]);
}

// ================================================================ K4c: scan pass B
// same n-half split; y = cross-half shfl reduce + half-wave store.
__global__ __launch_bounds__(256, 4) void k4c_scanB(
    const float* __restrict__ dltf, const float* __restrict__ dltr,
    const float* __restrict__ dtwf, const float* __restrict__ dtbf,
    const float* __restrict__ dtwr, const float* __restrict__ dtbr,
    const float* __restrict__ uf,  const float* __restrict__ ur,
    const float* __restrict__ Bf,  const float* __restrict__ Br,
    const float* __restrict__ Cf,  const float* __restrict__ Cr,
    const float* __restrict__ Alf, const float* __restrict__ Alr,
    const float* __restrict__ Dvf, const float* __restrict__ Dvr,
    const float* __restrict__ Hpre, float* __restrict__ yf, float* __restrict__ yr)
{
  int g = blockIdx.x*256 + threadIdx.x;
  int lane = threadIdx.x & 63;
  int nh = lane >> 5, dlo = lane & 31;
  int dhi = (g >> 6) & 1;
  int d = dhi*32 + dlo;
  int c = (g >> 7) & (NCH-1);
  int dir = (g >> 15) & 1;
  int b = g >> 16;
  const float* dlt = dir ? dltr : dltf;
  const float* u  = dir ? ur  : uf;
  const float* Bm = dir ? Br  : Bf;
  const float* Cm = dir ? Cr  : Cf;
  const float* Al = dir ? Alr : Alf;
  float4 wd = ((const float4*)(dir ? dtwr : dtwf))[d];
  float bd = (dir ? dtbr : dtbf)[d];
  float Dd = (dir ? Dvr : Dvf)[d];
  float* y = dir ? yr : yf;
  size_t pidx = (((size_t)(b*2+dir)*NCH + c)*64 + d)*16 + nh*8;
  float4 h0 = ((const float4*)(Hpre+pidx))[0];
  float4 h1 = ((const float4*)(Hpre+pidx))[1];
  float h[8] = {h0.x,h0.y,h0.z,h0.w, h1.x,h1.y,h1.z,h1.w};
  float A2[8];
  #pragma unroll
  for (int j = 0; j < 8; j++) A2[j] = -__expf(Al[d*16 + nh*8 + j]) * 1.44269504f;
  size_t base = (size_t)b*SEQL;
  int stp = dir ? -1 : 1;
  size_t tok = base + (dir ? (SEQL-1 - c*CHL) : (c*CHL));
  float4 dl = *(const float4*)(dlt + tok*4);
  float uvv = u[tok*64 + d];
  const float4* B4 = (const float4*)(Bm + tok*16 + nh*8);
  const float4* C4 = (const float4*)(Cm + tok*16 + nh*8);
  float4 qb0 = B4[0], qb1 = B4[1];
  float4 qc0 = C4[0], qc1 = C4[1];
  #pragma unroll 2
  for (int i = 0; i < CHL; i++){
    float4 dc = dl; float uc = uvv;
    float4 pb0 = qb0, pb1 = qb1;
    float4 pc0 = qc0, pc1 = qc1;
    size_t tok_c = tok;
    if (i + 1 < CHL){
      tok += stp;
      dl = *(const float4*)(dlt + tok*4);
      uvv = u[tok*64 + d];
      const float4* Bn = (const float4*)(Bm + tok*16 + nh*8);
      const float4* Cn = (const float4*)(Cm + tok*16 + nh*8);
      qb0 = Bn[0]; qb1 = Bn[1];
      qc0 = Cn[0]; qc1 = Cn[1];
    }
    float dtv = softplusf(wd.x*dc.x + wd.y*dc.y + wd.z*dc.z + wd.w*dc.w + bd);
    float du = dtv*uc;
    float bb[8] = {pb0.x,pb0.y,pb0.z,pb0.w, pb1.x,pb1.y,pb1.z,pb1.w};
    float cc[8] = {pc0.x,pc0.y,pc0.z,pc0.w, pc1.x,pc1.y,pc1.z,pc1.w};
    float yv = nh ? 0.f : uc*Dd;
    #pragma unroll
    for (int j = 0; j < 8; j++){
      float a = exp2f(dtv*A2[j]);
      h[j] = fmaf(a, h[j], du*bb[j]);
      yv = fmaf(h[j], cc[j], yv);
    }
    yv += __shfl_xor(yv, 32, 64);
    if (nh == 0) y[tok_c*64 + d] = yv;
  }
}

// ================================================================ G3: epilogue
__global__ __launch_bounds__(256) void g3_post(
    const float* __restrict__ yf, const float* __restrict__ yr,
    const unsigned short* __restrict__ zb, const unsigned short* __restrict__ zeb,
    const float* __restrict__ wg, const float* __restrict__ x0n,
    const float* __restrict__ in0,
    const float* __restrict__ mnw, const float* __restrict__ opw,
    const float* __restrict__ pnw, const float* __restrict__ pnb,
    float* __restrict__ out)
{
  __shared__ __align__(16) short Wl[64*72];
  __shared__ __align__(16) short Al[64*72];
  __shared__ float Dbuf[64*66];
  int tid = threadIdx.x;
  int t0 = blockIdx.x * 64;
  for (int sseg = tid; sseg < 64*8; sseg += 256){
    int row = sseg >> 3, sg = sseg & 7;
    const float* src = opw + (size_t)row*64 + sg*8;
    float4 f0 = ((const float4*)src)[0];
    float4 f1 = ((const float4*)src)[1];
    short8 v;
    v[0]=(short)f2b(f0.x); v[1]=(short)f2b(f0.y); v[2]=(short)f2b(f0.z); v[3]=(short)f2b(f0.w);
    v[4]=(short)f2b(f1.x); v[5]=(short)f2b(f1.y); v[6]=(short)f2b(f1.z); v[7]=(short)f2b(f1.w);
    *(short8*)&Wl[row*72 + sg*8] = v;
  }
  {
    int tl = tid >> 2, p = tid & 3;
    size_t g = (size_t)(t0 + tl)*64 + p*16;
    float4 yf4[4], yr4[4];
    #pragma unroll
    for (int i = 0; i < 4; i++){
      yf4[i] = ((const float4*)(yf + g))[i];
      yr4[i] = ((const float4*)(yr + g))[i];
    }
    short8 z8a  = *(const short8*)(zb + g);
    short8 z8b  = *(const short8*)(zb + g + 8);
    short8 ze8a = *(const short8*)(zeb + g);
    short8 ze8b = *(const short8*)(zeb + g + 8);
    float vy[16]; float ss = 0.f;
    #pragma unroll
    for (int i = 0; i < 16; i++){
      float yfv = ((const float*)yf4)[i];
      float yrv = ((const float*)yr4)[i];
      float zv  = b2f((unsigned short)(i < 8 ? z8a[i] : z8b[i-8]));
      float zev = b2f((unsigned short)(i < 8 ? ze8a[i] : ze8b[i-8]));
      float v = 0.5f*(yfv*siluf(zv) + yrv*siluf(zev));
      vy[i] = v; ss += v*v;
    }
    ss += __shfl_xor(ss, 1, 64);
    ss += __shfl_xor(ss, 2, 64);
    float rms = rsqrtf(ss*(1.f/64.f) + 1e-5f);
    #pragma unroll
    for (int i = 0; i < 16; i++){
      float w = mnw[p*16 + i];
      Al[tl*72 + p*16 + i] = (short)f2b(vy[i]*rms*w);
    }
  }
  __syncthreads();
  int lane = tid & 63, wv = tid >> 6;
  int n = lane & 15, q = lane >> 4;
  {
    short8 a0 = *(const short8*)&Al[(wv*16 + n)*72 + q*8];
    short8 a1 = *(const short8*)&Al[(wv*16 + n)*72 + 32 + q*8];
    #pragma unroll
    for (int o = 0; o < 4; ++o){
      short8 b0 = *(const short8*)&Wl[(o*16 + n)*72 + q*8];
      short8 b1 = *(const short8*)&Wl[(o*16 + n)*72 + 32 + q*8];
      f32x4 c = {0.f, 0.f, 0.f, 0.f};
      c = __builtin_amdgcn_mfma_f32_16x16x32_bf16(a0, b0, c, 0, 0, 0);
      c = __builtin_amdgcn_mfma_f32_16x16x32_bf16(a1, b1, c, 0, 0, 0);
      #pragma unroll
      for (int r = 0; r < 4; ++r)
        Dbuf[(wv*16 + q*4 + r)*66 + o*16 + n] = c[r];
    }
  }
  __syncthreads();
  float gpw = pnw[lane], gpb = pnb[lane];
  float s1, s2;
  for (int i = 0; i < 16; ++i){
    int tl = wv*16 + i;
    size_t off = (size_t)(t0 + tl)*64 + lane;
    float v = Dbuf[tl*66 + lane];
    s1 = v; s2 = v*v;
    #pragma unroll
    for (int o2 = 32; o2 > 0; o2 >>= 1){ s1 += __shfl_xor(s1,o2,64); s2 += __shfl_xor(s2,o2,64); }
    float m = s1*(1.f/64.f);
    float qv = s2*(1.f/64.f) - m*m;
    float o = (v-m)*rsqrtf(qv+1e-5f)*gpw + gpb;
    o = nan2num(o, 0.f, 1.f, -1.f);
    float w = wg[off];
    float skip = nan2num(in0[off], 0.f, 1.f, -1.f);
    out[off] = fmaf(o, w, fmaf(x0n[off], 1.f - w, skip));
  }
}

// ================================================================ launcher
extern "C" void kernel_launch(void* const* d_in, const int* in_sizes, int n_in,
                              void* d_out, int out_size, void* d_ws, size_t ws_size,
                              hipStream_t stream)
{
  (void)in_sizes; (void)n_in; (void)out_size; (void)ws_size;
  const float* in0  = (const float*)d_in[0];
  const float* in1  = (const float*)d_in[1];
  const float* n0w  = (const float*)d_in[2];
  const float* n0b  = (const float*)d_in[3];
  const float* n1w  = (const float*)d_in[4];
  const float* n1b  = (const float*)d_in[5];
  const float* cww  = (const float*)d_in[6];
  const float* cwb  = (const float*)d_in[7];
  const float* cwnw = (const float*)d_in[8];
  const float* cwnb = (const float*)d_in[9];
  const float* ipw  = (const float*)d_in[10];
  const float* ipew = (const float*)d_in[11];
  const float* cwf  = (const float*)d_in[12];
  const float* cbf  = (const float*)d_in[13];
  const float* xpwf = (const float*)d_in[14];
  const float* dtwf = (const float*)d_in[15];
  const float* dtbf = (const float*)d_in[16];
  const float* Alf  = (const float*)d_in[17];
  const float* Dvf  = (const float*)d_in[18];
  const float* cwr  = (const float*)d_in[19];
  const float* cbr  = (const float*)d_in[20];
  const float* xpwr = (const float*)d_in[21];
  const float* dtwr = (const float*)d_in[22];
  const float* dtbr = (const float*)d_in[23];
  const float* Alr  = (const float*)d_in[24];
  const float* Dvr  = (const float*)d_in[25];
  const float* mnw  = (const float*)d_in[26];
  const float* opw  = (const float*)d_in[27];
  const float* pnw  = (const float*)d_in[28];
  const float* pnb  = (const float*)d_in[29];

  float* ws  = (float*)d_ws;
  float* x0n = ws + 0*EL;
  float* xa  = ws + 1*EL;   // conv input fwd; reused as yf
  float* xe  = ws + 2*EL;   // conv input rev; reused as yr
  float* uf  = ws + 3*EL;
  float* ur  = ws + 4*EL;
  float* wg  = ws + 5*EL;
  float* Bf  = ws + 6*EL;              // TOK*16 each (4 arrays = EL total)
  float* Cf  = Bf + (size_t)TOK*16;
  float* Br  = Cf + (size_t)TOK*16;
  float* Cr  = Br + (size_t)TOK*16;
  float* P   = ws + 7*EL;              // 2*TOK*16 floats = EL/2
  float* S   = P + 2*(size_t)TOK*16;   // EL/2
  unsigned short* zb  = (unsigned short*)(ws + 8*EL);
  unsigned short* zeb = zb + EL;
  float* dltf = ws + 9*EL;             // TOK*4 each
  float* dltr = dltf + (size_t)TOK*4;
  float* yfp = xa;
  float* yrp = xe;

  mega1<<<512, 256, 0, stream>>>(in0, in1, n0w, n0b, n1w, n1b, cww, cwb,
                                 cwnw, cwnb, ipw, ipew,
                                 x0n, wg, xa, xe, zb, zeb);
  g2_convproj<<<512, 256, 0, stream>>>(xa, xe, cwf, cbf, cwr, cbr,
                                       xpwf, xpwr,
                                       uf, ur, dltf, dltr, Bf, Cf, Br, Cr);
  k4a_scanA<<<1024, 256, 0, stream>>>(dltf, dltr, dtwf, dtbf, dtwr, dtbr,
                                      uf, ur, Bf, Br, Alf, Alr, P, S);
  k4b_ks<<<512, 256, 0, stream>>>(P, S);
  k4c_scanB<<<1024, 256, 0, stream>>>(dltf, dltr, dtwf, dtbf, dtwr, dtbr,
                                      uf, ur, Bf, Br, Cf, Cr,
                                      Alf, Alr, Dvf, Dvr, P, yfp, yrp);
  g3_post<<<1024, 256, 0, stream>>>(yfp, yrp, zb, zeb, wg, x0n, in0,
                                    mnw, opw, pnw, pnb, (float*)d_out);
}

// Round 6
// 361.738 us; speedup vs baseline: 1.1211x; 1.1181x over previous
//
#include <hip/hip_runtime.h>
#include <stdint.h>

#define BATCH 4
#define SEQL  16384
#define DIM   64
#define NST   16
#define TOK   (BATCH*SEQL)        /* 65536 tokens */
#define EL    ((size_t)TOK*DIM)   /* 4194304 elems per [B,L,D] array */
#define NCH   256                 /* chunks per (b,dir) */
#define CHL   64                  /* chunk length; NCH*CHL == SEQL */

typedef __attribute__((ext_vector_type(8))) short short8;
typedef __attribute__((ext_vector_type(4))) float f32x4;

__device__ __forceinline__ float nan2num(float x, float nv, float pv, float mv){
  if (__builtin_isnan(x)) return nv;
  if (__builtin_isinf(x)) return x > 0.f ? pv : mv;
  return x;
}
__device__ __forceinline__ float siluf(float x){ return x / (1.f + __expf(-x)); }
__device__ __forceinline__ float b2f(unsigned short s){
  union { unsigned u; float f; } v; v.u = ((unsigned)s) << 16; return v.f;
}
__device__ __forceinline__ unsigned short f2b(float f){
  union { float f; unsigned u; } v; v.f = f;
  unsigned r = v.u + 0x7fffu + ((v.u >> 16) & 1u);   // RNE
  return (unsigned short)(r >> 16);
}
// fast softplus: ln(1+e^x) = log2(1+2^(x*log2e))*ln2  (HW v_exp/v_log, no libm)
__device__ __forceinline__ float softplus_fast(float x){
  if (x > 20.f) return x;
  float t = exp2f(x * 1.44269504f);
  return __log2f(1.f + t) * 0.69314718f;
}

// ================================================================ MEGA1
__global__ __launch_bounds__(256) void mega1(
    const float* __restrict__ in0, const float* __restrict__ in1,
    const float* __restrict__ n0w, const float* __restrict__ n0b,
    const float* __restrict__ n1w, const float* __restrict__ n1b,
    const float* __restrict__ cww, const float* __restrict__ cwb,
    const float* __restrict__ cwnw, const float* __restrict__ cwnb,
    const float* __restrict__ ipw, const float* __restrict__ ipew,
    float* __restrict__ x0n, float* __restrict__ wg,
    float* __restrict__ xa,  float* __restrict__ xe,
    unsigned short* __restrict__ zb, unsigned short* __restrict__ zeb)
{
  __shared__ __align__(16) short Wl[192*72];
  __shared__ __align__(16) short Al[128*72];
  int tid = threadIdx.x;
  int t0 = blockIdx.x * 128;
  int lane = tid & 63, wv = tid >> 6;
  int n = lane & 15, q = lane >> 4;
  f32x4 wacc[2][4];

  #pragma unroll
  for (int s = 0; s < 2; ++s){
    const float* ips = s ? ipew : ipw;
    for (int sseg = tid; sseg < 192*8; sseg += 256){
      int row = sseg >> 3, sg = sseg & 7;
      const float* src = (row < 64) ? (cww + (size_t)row*128 + s*64 + sg*8)
                                    : (ips + (size_t)(row-64)*64 + sg*8);
      float4 f0 = ((const float4*)src)[0];
      float4 f1 = ((const float4*)src)[1];
      short8 v;
      v[0]=(short)f2b(f0.x); v[1]=(short)f2b(f0.y); v[2]=(short)f2b(f0.z); v[3]=(short)f2b(f0.w);
      v[4]=(short)f2b(f1.x); v[5]=(short)f2b(f1.y); v[6]=(short)f2b(f1.z); v[7]=(short)f2b(f1.w);
      *(short8*)&Wl[row*72 + sg*8] = v;
    }
    {
      const float* inp = s ? in1 : in0;
      const float* nw  = s ? n1w : n0w;
      const float* nb  = s ? n1b : n0b;
      int tl = tid >> 2, p = tid & 3;
      float gw[16], gb[16];
      #pragma unroll
      for (int i = 0; i < 4; ++i){
        float4 w4 = ((const float4*)(nw + p*16))[i];
        float4 b4 = ((const float4*)(nb + p*16))[i];
        gw[4*i]=w4.x; gw[4*i+1]=w4.y; gw[4*i+2]=w4.z; gw[4*i+3]=w4.w;
        gb[4*i]=b4.x; gb[4*i+1]=b4.y; gb[4*i+2]=b4.z; gb[4*i+3]=b4.w;
      }
      #pragma unroll
      for (int sp = 0; sp < 2; ++sp){
        int tok_l = sp*64 + tl;
        size_t ga = ((size_t)(t0 + tok_l))*64 + p*16;
        float v[16]; float s1 = 0.f, s2 = 0.f;
        #pragma unroll
        for (int i = 0; i < 4; ++i){
          float4 f = ((const float4*)(inp + ga))[i];
          float a0 = nan2num(f.x,0.f,1.f,-1.f), a1 = nan2num(f.y,0.f,1.f,-1.f);
          float a2 = nan2num(f.z,0.f,1.f,-1.f), a3 = nan2num(f.w,0.f,1.f,-1.f);
          v[4*i]=a0; v[4*i+1]=a1; v[4*i+2]=a2; v[4*i+3]=a3;
          s1 += a0+a1+a2+a3; s2 += a0*a0+a1*a1+a2*a2+a3*a3;
        }
        s1 += __shfl_xor(s1,1,64); s1 += __shfl_xor(s1,2,64);
        s2 += __shfl_xor(s2,1,64); s2 += __shfl_xor(s2,2,64);
        float m = s1*(1.f/64.f);
        float var = s2*(1.f/64.f) - m*m;
        float rs = rsqrtf(var + 1e-5f);
        float xr[16];
        #pragma unroll
        for (int i = 0; i < 16; ++i){
          float x = nan2num((v[i]-m)*rs*gw[i] + gb[i], 0.f, 1.f, -1.f);
          xr[i] = x;
          Al[tok_l*72 + p*16 + i] = (short)f2b(x);
        }
        if (s == 0){
          #pragma unroll
          for (int i = 0; i < 4; ++i)
            ((float4*)(x0n + ga))[i] = make_float4(xr[4*i],xr[4*i+1],xr[4*i+2],xr[4*i+3]);
        }
      }
    }
    __syncthreads();
    float* outx = s ? xe : xa;
    unsigned short* outz = s ? zeb : zb;
    #pragma unroll
    for (int mi = 0; mi < 2; ++mi){
      int mt = wv*2 + mi;
      short8 a0 = *(const short8*)&Al[(mt*16 + n)*72 + q*8];
      short8 a1 = *(const short8*)&Al[(mt*16 + n)*72 + 32 + q*8];
      #pragma unroll
      for (int o = 0; o < 12; ++o){
        short8 b0 = *(const short8*)&Wl[(o*16 + n)*72 + q*8];
        short8 b1 = *(const short8*)&Wl[(o*16 + n)*72 + 32 + q*8];
        f32x4 c = {0.f, 0.f, 0.f, 0.f};
        c = __builtin_amdgcn_mfma_f32_16x16x32_bf16(a0, b0, c, 0, 0, 0);
        c = __builtin_amdgcn_mfma_f32_16x16x32_bf16(a1, b1, c, 0, 0, 0);
        if (o < 4){
          if (s == 0) wacc[mi][o] = c; else wacc[mi][o] += c;
        } else if (o < 8){
          #pragma unroll
          for (int r = 0; r < 4; ++r)
            outx[((size_t)(t0 + mt*16 + q*4 + r))*64 + (o-4)*16 + n] = c[r];
        } else {
          #pragma unroll
          for (int r = 0; r < 4; ++r)
            outz[((size_t)(t0 + mt*16 + q*4 + r))*64 + (o-8)*16 + n] = f2b(c[r]);
        }
      }
    }
    if (s == 0) __syncthreads();
  }
  float cb_l[4], gnw[4], gnb[4];
  #pragma unroll
  for (int o = 0; o < 4; ++o){
    cb_l[o] = cwb[o*16+n]; gnw[o] = cwnw[o*16+n]; gnb[o] = cwnb[o*16+n];
  }
  #pragma unroll
  for (int mi = 0; mi < 2; ++mi){
    #pragma unroll
    for (int r = 0; r < 4; ++r){
      float v[4]; float sv = 0.f, sq = 0.f;
      #pragma unroll
      for (int o = 0; o < 4; ++o){
        v[o] = wacc[mi][o][r] + cb_l[o];
        sv += v[o]; sq += v[o]*v[o];
      }
      sv += __shfl_xor(sv,1,64); sv += __shfl_xor(sv,2,64);
      sv += __shfl_xor(sv,4,64); sv += __shfl_xor(sv,8,64);
      sq += __shfl_xor(sq,1,64); sq += __shfl_xor(sq,2,64);
      sq += __shfl_xor(sq,4,64); sq += __shfl_xor(sq,8,64);
      float m = sv*(1.f/64.f);
      float var = sq*(1.f/64.f) - m*m;
      float rs = rsqrtf(var + 1e-5f);
      size_t tok = (size_t)t0 + (wv*2+mi)*16 + q*4 + r;
      #pragma unroll
      for (int o = 0; o < 4; ++o){
        float wn = (v[o]-m)*rs*gnw[o] + gnb[o];
        wn = nan2num(wn, 0.5f, 1.f, 0.f);
        wn = 1.f/(1.f + __expf(-wn));
        wn = fminf(fmaxf(wn, 0.01f), 0.99f);
        wg[tok*64 + o*16 + n] = wn;
      }
    }
  }
}

// ================================================================ G2: conv + xproj
__global__ __launch_bounds__(256) void g2_convproj(
    const float* __restrict__ xa, const float* __restrict__ xe,
    const float* __restrict__ cwf, const float* __restrict__ cbf,
    const float* __restrict__ cwr, const float* __restrict__ cbr,
    const float* __restrict__ xpwf, const float* __restrict__ xpwr,
    float* __restrict__ uf, float* __restrict__ ur,
    float* __restrict__ dltf, float* __restrict__ dltr,
    float* __restrict__ Bf, float* __restrict__ Cf,
    float* __restrict__ Br, float* __restrict__ Cr)
{
  __shared__ __align__(16) short Wl[2*48*72];
  __shared__ __align__(16) short Al[2*128*72];
  int tid = threadIdx.x;
  int b = blockIdx.x >> 7, l0 = (blockIdx.x & 127) * 128;
  size_t base = (size_t)b * SEQL;
  for (int sseg = tid; sseg < 2*48*8; sseg += 256){
    int s = sseg >= 48*8;
    int rs = sseg - s*48*8;
    int row = rs >> 3, sg = rs & 7;
    const float* xp = s ? xpwr : xpwf;
    short8 v = {0,0,0,0,0,0,0,0};
    int srcrow = (row < 32) ? (4+row) : (row < 36) ? (row-32) : -1;
    if (srcrow >= 0){
      const float* src = xp + (size_t)srcrow*64 + sg*8;
      float4 f0 = ((const float4*)src)[0];
      float4 f1 = ((const float4*)src)[1];
      v[0]=(short)f2b(f0.x); v[1]=(short)f2b(f0.y); v[2]=(short)f2b(f0.z); v[3]=(short)f2b(f0.w);
      v[4]=(short)f2b(f1.x); v[5]=(short)f2b(f1.y); v[6]=(short)f2b(f1.z); v[7]=(short)f2b(f1.w);
    }
    *(short8*)&Wl[(s*48+row)*72 + sg*8] = v;
  }
  {
    int d = tid & 63, lq = tid >> 6;
    float4 wf4 = ((const float4*)cwf)[d];
    float4 wr4 = ((const float4*)cwr)[d];
    float bf = cbf[d], brr = cbr[d];
    for (int i = 0; i < 8; ++i){
      int ll = i*16 + lq*4;
      int gl = l0 + ll;
      float rv[7], sv[7];
      #pragma unroll
      for (int j = 0; j < 7; ++j){
        int li = gl - 3 + j;
        rv[j] = (li >= 0) ? xa[(base + li)*64 + d] : 0.f;
        int lj = gl + j;
        sv[j] = (lj < SEQL) ? xe[(base + lj)*64 + d] : 0.f;
      }
      #pragma unroll
      for (int k = 0; k < 4; ++k){
        float a = bf + wf4.x*rv[k] + wf4.y*rv[k+1] + wf4.z*rv[k+2] + wf4.w*rv[k+3];
        a = siluf(a);
        uf[(base + gl + k)*64 + d] = a;
        Al[(ll+k)*72 + d] = (short)f2b(a);
        float r = brr + wr4.w*sv[k] + wr4.z*sv[k+1] + wr4.y*sv[k+2] + wr4.x*sv[k+3];
        r = siluf(r);
        ur[(base + gl + k)*64 + d] = r;
        Al[(128 + ll + k)*72 + d] = (short)f2b(r);
      }
    }
  }
  __syncthreads();
  int lane = tid & 63, wv = tid >> 6;
  int n = lane & 15, q = lane >> 4;
  #pragma unroll
  for (int s = 0; s < 2; ++s){
    const short* As = &Al[s*128*72];
    const short* Ws = &Wl[s*48*72];
    float* Bo = s ? Br : Bf;
    float* Co = s ? Cr : Cf;
    float* Do = s ? dltr : dltf;
    #pragma unroll
    for (int mi = 0; mi < 2; ++mi){
      int mt = wv*2 + mi;
      short8 a0 = *(const short8*)&As[(mt*16 + n)*72 + q*8];
      short8 a1 = *(const short8*)&As[(mt*16 + n)*72 + 32 + q*8];
      f32x4 acc[3];
      #pragma unroll
      for (int o = 0; o < 3; ++o){
        short8 b0 = *(const short8*)&Ws[(o*16 + n)*72 + q*8];
        short8 b1 = *(const short8*)&Ws[(o*16 + n)*72 + 32 + q*8];
        f32x4 c = {0.f, 0.f, 0.f, 0.f};
        c = __builtin_amdgcn_mfma_f32_16x16x32_bf16(a0, b0, c, 0, 0, 0);
        c = __builtin_amdgcn_mfma_f32_16x16x32_bf16(a1, b1, c, 0, 0, 0);
        acc[o] = c;
      }
      #pragma unroll
      for (int r = 0; r < 4; ++r){
        size_t tok = base + l0 + mt*16 + q*4 + r;
        Bo[tok*16 + n] = acc[0][r];
        Co[tok*16 + n] = acc[1][r];
        if (n < 4) Do[tok*4 + n] = acc[2][r];
      }
    }
  }
}

// ---------------------------------------------------------------- scan slots
struct SlotA { float4 dl; float uv; float4 b0, b1; };
struct SlotC { float4 dl; float uv; float4 b0, b1, c0, c1; };

__device__ __forceinline__ void ldA(SlotA& s, const float* __restrict__ dlt,
                                    const float* __restrict__ u,
                                    const float* __restrict__ Bm,
                                    size_t tok, int d, int nh){
  s.dl = *(const float4*)(dlt + tok*4);
  s.uv = u[tok*64 + d];
  const float4* Bp = (const float4*)(Bm + tok*16 + nh*8);
  s.b0 = Bp[0]; s.b1 = Bp[1];
}
__device__ __forceinline__ void ldC(SlotC& s, const float* __restrict__ dlt,
                                    const float* __restrict__ u,
                                    const float* __restrict__ Bm,
                                    const float* __restrict__ Cm,
                                    size_t tok, int d, int nh){
  s.dl = *(const float4*)(dlt + tok*4);
  s.uv = u[tok*64 + d];
  const float4* Bp = (const float4*)(Bm + tok*16 + nh*8);
  const float4* Cp = (const float4*)(Cm + tok*16 + nh*8);
  s.b0 = Bp[0]; s.b1 = Bp[1];
  s.c0 = Cp[0]; s.c1 = Cp[1];
}
__device__ __forceinline__ void consA(const SlotA& s, const float4& wd, float bd,
                                      const float (&A2)[8], float (&Pp)[8], float (&Ss)[8]){
  float dtv = softplus_fast(fmaf(wd.x,s.dl.x, fmaf(wd.y,s.dl.y,
                            fmaf(wd.z,s.dl.z, fmaf(wd.w,s.dl.w, bd)))));
  float du = dtv * s.uv;
  float bb[8] = {s.b0.x,s.b0.y,s.b0.z,s.b0.w, s.b1.x,s.b1.y,s.b1.z,s.b1.w};
  #pragma unroll
  for (int j = 0; j < 8; j++){
    float a = exp2f(dtv*A2[j]);
    Pp[j] *= a;
    Ss[j] = fmaf(a, Ss[j], du*bb[j]);
  }
}
__device__ __forceinline__ void consC(const SlotC& s, const float4& wd, float bd, float Dd,
                                      const float (&A2)[8], float (&h)[8],
                                      float* __restrict__ y, size_t tokS, int d, int nh){
  float dtv = softplus_fast(fmaf(wd.x,s.dl.x, fmaf(wd.y,s.dl.y,
                            fmaf(wd.z,s.dl.z, fmaf(wd.w,s.dl.w, bd)))));
  float du = dtv * s.uv;
  float bb[8] = {s.b0.x,s.b0.y,s.b0.z,s.b0.w, s.b1.x,s.b1.y,s.b1.z,s.b1.w};
  float cc[8] = {s.c0.x,s.c0.y,s.c0.z,s.c0.w, s.c1.x,s.c1.y,s.c1.z,s.c1.w};
  float yv = nh ? 0.f : s.uv*Dd;
  #pragma unroll
  for (int j = 0; j < 8; j++){
    float a = exp2f(dtv*A2[j]);
    h[j] = fmaf(a, h[j], du*bb[j]);
    yv = fmaf(h[j], cc[j], yv);
  }
  yv += __shfl_xor(yv, 32, 64);
  if (nh == 0) y[tokS*64 + d] = yv;
}

// ================================================================ K4a: chunk compose
// thread = (b,dir,chunk,d,n-half); depth-4 register-pipelined loads.
__global__ __launch_bounds__(256, 4) void k4a_scanA(
    const float* __restrict__ dltf, const float* __restrict__ dltr,
    const float* __restrict__ dtwf, const float* __restrict__ dtbf,
    const float* __restrict__ dtwr, const float* __restrict__ dtbr,
    const float* __restrict__ uf,  const float* __restrict__ ur,
    const float* __restrict__ Bf,  const float* __restrict__ Br,
    const float* __restrict__ Alf, const float* __restrict__ Alr,
    float* __restrict__ P, float* __restrict__ S)
{
  int g = blockIdx.x*256 + threadIdx.x;     // 262144 threads
  int lane = threadIdx.x & 63;
  int nh = lane >> 5, dlo = lane & 31;
  int dhi = (g >> 6) & 1;
  int d = dhi*32 + dlo;
  int c = (g >> 7) & (NCH-1);
  int dir = (g >> 15) & 1;
  int b = g >> 16;
  const float* dlt = dir ? dltr : dltf;
  const float* u  = dir ? ur  : uf;
  const float* Bm = dir ? Br  : Bf;
  const float* Al = dir ? Alr : Alf;
  float4 wd = ((const float4*)(dir ? dtwr : dtwf))[d];
  float bd = (dir ? dtbr : dtbf)[d];
  float A2[8], Pp[8], Ss[8];
  #pragma unroll
  for (int j = 0; j < 8; j++){
    A2[j] = -__expf(Al[d*16 + nh*8 + j]) * 1.44269504f;
    Pp[j] = 1.f; Ss[j] = 0.f;
  }
  size_t base = (size_t)b*SEQL;
  int stp = dir ? -1 : 1;
  size_t tokL = base + (dir ? (SEQL-1 - c*CHL) : (c*CHL));
  SlotA s0, s1, s2, s3;
  ldA(s0, dlt, u, Bm, tokL, d, nh); tokL += stp;
  ldA(s1, dlt, u, Bm, tokL, d, nh); tokL += stp;
  ldA(s2, dlt, u, Bm, tokL, d, nh); tokL += stp;
  ldA(s3, dlt, u, Bm, tokL, d, nh); tokL += stp;
  for (int i = 0; i < CHL; i += 4){
    consA(s0, wd, bd, A2, Pp, Ss);
    if (i+4 < CHL){ ldA(s0, dlt, u, Bm, tokL, d, nh); tokL += stp; }
    consA(s1, wd, bd, A2, Pp, Ss);
    if (i+5 < CHL){ ldA(s1, dlt, u, Bm, tokL, d, nh); tokL += stp; }
    consA(s2, wd, bd, A2, Pp, Ss);
    if (i+6 < CHL){ ldA(s2, dlt, u, Bm, tokL, d, nh); tokL += stp; }
    consA(s3, wd, bd, A2, Pp, Ss);
    if (i+7 < CHL){ ldA(s3, dlt, u, Bm, tokL, d, nh); tokL += stp; }
  }
  size_t pidx = (((size_t)(b*2+dir)*NCH + c)*64 + d)*16 + nh*8;
  ((float4*)(P+pidx))[0] = make_float4(Pp[0],Pp[1],Pp[2],Pp[3]);
  ((float4*)(P+pidx))[1] = make_float4(Pp[4],Pp[5],Pp[6],Pp[7]);
  ((float4*)(S+pidx))[0] = make_float4(Ss[0],Ss[1],Ss[2],Ss[3]);
  ((float4*)(S+pidx))[1] = make_float4(Ss[4],Ss[5],Ss[6],Ss[7]);
}

// ================================================================ K4b: Kogge-Stone carry scan
__global__ __launch_bounds__(256) void k4b_ks(float* __restrict__ P,
                                              const float* __restrict__ S)
{
  __shared__ float Pl[256*18], Sl[256*18];
  int c = threadIdx.x;
  int d = blockIdx.x & 63, bd = blockIdx.x >> 6;
  size_t idx = (((size_t)bd*NCH + c)*64 + d)*16;
  float p[16], s[16];
  #pragma unroll
  for (int k = 0; k < 4; k++){
    float4 pv = ((const float4*)(P + idx))[k];
    float4 sv = ((const float4*)(S + idx))[k];
    p[4*k]=pv.x; p[4*k+1]=pv.y; p[4*k+2]=pv.z; p[4*k+3]=pv.w;
    s[4*k]=sv.x; s[4*k+1]=sv.y; s[4*k+2]=sv.z; s[4*k+3]=sv.w;
  }
  #pragma unroll
  for (int j = 0; j < 8; j++){
    *(float2*)&Pl[c*18 + 2*j] = make_float2(p[2*j], p[2*j+1]);
    *(float2*)&Sl[c*18 + 2*j] = make_float2(s[2*j], s[2*j+1]);
  }
  for (int step = 1; step < NCH; step <<= 1){
    __syncthreads();
    float pp[16], ss[16];
    bool act = (c >= step);
    if (act){
      #pragma unroll
      for (int j = 0; j < 8; j++){
        float2 tp = *(const float2*)&Pl[(c-step)*18 + 2*j];
        float2 ts = *(const float2*)&Sl[(c-step)*18 + 2*j];
        pp[2*j]=tp.x; pp[2*j+1]=tp.y; ss[2*j]=ts.x; ss[2*j+1]=ts.y;
      }
    }
    __syncthreads();
    if (act){
      #pragma unroll
      for (int n = 0; n < 16; n++){
        s[n] = fmaf(p[n], ss[n], s[n]);
        p[n] *= pp[n];
      }
      #pragma unroll
      for (int j = 0; j < 8; j++){
        *(float2*)&Pl[c*18 + 2*j] = make_float2(p[2*j], p[2*j+1]);
        *(float2*)&Sl[c*18 + 2*j] = make_float2(s[2*j], s[2*j+1]);
      }
    }
  }
  __syncthreads();
  float ho[16];
  if (c == 0){
    #pragma unroll
    for (int n = 0; n < 16; n++) ho[n] = 0.f;
  } else {
    #pragma unroll
    for (int j = 0; j < 8; j++){
      float2 ts = *(const float2*)&Sl[(c-1)*18 + 2*j];
      ho[2*j]=ts.x; ho[2*j+1]=ts.y;
    }
  }
  #pragma unroll
  for (int k = 0; k < 4; k++)
    ((float4*)(P + idx))[k] = make_float4(ho[4*k], ho[4*k+1], ho[4*k+2], ho[4*k+3]);
}

// ================================================================ K4c: scan pass B
// n-half split + depth-4 register-pipelined loads; cross-half shfl reduce for y.
__global__ __launch_bounds__(256, 3) void k4c_scanB(
    const float* __restrict__ dltf, const float* __restrict__ dltr,
    const float* __restrict__ dtwf, const float* __restrict__ dtbf,
    const float* __restrict__ dtwr, const float* __restrict__ dtbr,
    const float* __restrict__ uf,  const float* __restrict__ ur,
    const float* __restrict__ Bf,  const float* __restrict__ Br,
    const float* __restrict__ Cf,  const float* __restrict__ Cr,
    const float* __restrict__ Alf, const float* __restrict__ Alr,
    const float* __restrict__ Dvf, const float* __restrict__ Dvr,
    const float* __restrict__ Hpre, float* __restrict__ yf, float* __restrict__ yr)
{
  int g = blockIdx.x*256 + threadIdx.x;
  int lane = threadIdx.x & 63;
  int nh = lane >> 5, dlo = lane & 31;
  int dhi = (g >> 6) & 1;
  int d = dhi*32 + dlo;
  int c = (g >> 7) & (NCH-1);
  int dir = (g >> 15) & 1;
  int b = g >> 16;
  const float* dlt = dir ? dltr : dltf;
  const float* u  = dir ? ur  : uf;
  const float* Bm = dir ? Br  : Bf;
  const float* Cm = dir ? Cr  : Cf;
  const float* Al = dir ? Alr : Alf;
  float4 wd = ((const float4*)(dir ? dtwr : dtwf))[d];
  float bd = (dir ? dtbr : dtbf)[d];
  float Dd = (dir ? Dvr : Dvf)[d];
  float* y = dir ? yr : yf;
  size_t pidx = (((size_t)(b*2+dir)*NCH + c)*64 + d)*16 + nh*8;
  float4 h0 = ((const float4*)(Hpre+pidx))[0];
  float4 h1 = ((const float4*)(Hpre+pidx))[1];
  float h[8] = {h0.x,h0.y,h0.z,h0.w, h1.x,h1.y,h1.z,h1.w};
  float A2[8];
  #pragma unroll
  for (int j = 0; j < 8; j++) A2[j] = -__expf(Al[d*16 + nh*8 + j]) * 1.44269504f;
  size_t base = (size_t)b*SEQL;
  int stp = dir ? -1 : 1;
  size_t tokL = base + (dir ? (SEQL-1 - c*CHL) : (c*CHL));
  size_t tokS = tokL;
  SlotC s0, s1, s2, s3;
  ldC(s0, dlt, u, Bm, Cm, tokL, d, nh); tokL += stp;
  ldC(s1, dlt, u, Bm, Cm, tokL, d, nh); tokL += stp;
  ldC(s2, dlt, u, Bm, Cm, tokL, d, nh); tokL += stp;
  ldC(s3, dlt, u, Bm, Cm, tokL, d, nh); tokL += stp;
  for (int i = 0; i < CHL; i += 4){
    consC(s0, wd, bd, Dd, A2, h, y, tokS, d, nh); tokS += stp;
    if (i+4 < CHL){ ldC(s0, dlt, u, Bm, Cm, tokL, d, nh); tokL += stp; }
    consC(s1, wd, bd, Dd, A2, h, y, tokS, d, nh); tokS += stp;
    if (i+5 < CHL){ ldC(s1, dlt, u, Bm, Cm, tokL, d, nh); tokL += stp; }
    consC(s2, wd, bd, Dd, A2, h, y, tokS, d, nh); tokS += stp;
    if (i+6 < CHL){ ldC(s2, dlt, u, Bm, Cm, tokL, d, nh); tokL += stp; }
    consC(s3, wd, bd, Dd, A2, h, y, tokS, d, nh); tokS += stp;
    if (i+7 < CHL){ ldC(s3, dlt, u, Bm, Cm, tokL, d, nh); tokL += stp; }
  }
}

// ================================================================ G3: epilogue
__global__ __launch_bounds__(256) void g3_post(
    const float* __restrict__ yf, const float* __restrict__ yr,
    const unsigned short* __restrict__ zb, const unsigned short* __restrict__ zeb,
    const float* __restrict__ wg, const float* __restrict__ x0n,
    const float* __restrict__ in0,
    const float* __restrict__ mnw, const float* __restrict__ opw,
    const float* __restrict__ pnw, const float* __restrict__ pnb,
    float* __restrict__ out)
{
  __shared__ __align__(16) short Wl[64*72];
  __shared__ __align__(16) short Al[64*72];
  __shared__ float Dbuf[64*66];
  int tid = threadIdx.x;
  int t0 = blockIdx.x * 64;
  for (int sseg = tid; sseg < 64*8; sseg += 256){
    int row = sseg >> 3, sg = sseg & 7;
    const float* src = opw + (size_t)row*64 + sg*8;
    float4 f0 = ((const float4*)src)[0];
    float4 f1 = ((const float4*)src)[1];
    short8 v;
    v[0]=(short)f2b(f0.x); v[1]=(short)f2b(f0.y); v[2]=(short)f2b(f0.z); v[3]=(short)f2b(f0.w);
    v[4]=(short)f2b(f1.x); v[5]=(short)f2b(f1.y); v[6]=(short)f2b(f1.z); v[7]=(short)f2b(f1.w);
    *(short8*)&Wl[row*72 + sg*8] = v;
  }
  {
    int tl = tid >> 2, p = tid & 3;
    size_t g = (size_t)(t0 + tl)*64 + p*16;
    float4 yf4[4], yr4[4];
    #pragma unroll
    for (int i = 0; i < 4; i++){
      yf4[i] = ((const float4*)(yf + g))[i];
      yr4[i] = ((const float4*)(yr + g))[i];
    }
    short8 z8a  = *(const short8*)(zb + g);
    short8 z8b  = *(const short8*)(zb + g + 8);
    short8 ze8a = *(const short8*)(zeb + g);
    short8 ze8b = *(const short8*)(zeb + g + 8);
    float vy[16]; float ss = 0.f;
    #pragma unroll
    for (int i = 0; i < 16; i++){
      float yfv = ((const float*)yf4)[i];
      float yrv = ((const float*)yr4)[i];
      float zv  = b2f((unsigned short)(i < 8 ? z8a[i] : z8b[i-8]));
      float zev = b2f((unsigned short)(i < 8 ? ze8a[i] : ze8b[i-8]));
      float v = 0.5f*(yfv*siluf(zv) + yrv*siluf(zev));
      vy[i] = v; ss += v*v;
    }
    ss += __shfl_xor(ss, 1, 64);
    ss += __shfl_xor(ss, 2, 64);
    float rms = rsqrtf(ss*(1.f/64.f) + 1e-5f);
    #pragma unroll
    for (int i = 0; i < 16; i++){
      float w = mnw[p*16 + i];
      Al[tl*72 + p*16 + i] = (short)f2b(vy[i]*rms*w);
    }
  }
  __syncthreads();
  int lane = tid & 63, wv = tid >> 6;
  int n = lane & 15, q = lane >> 4;
  {
    short8 a0 = *(const short8*)&Al[(wv*16 + n)*72 + q*8];
    short8 a1 = *(const short8*)&Al[(wv*16 + n)*72 + 32 + q*8];
    #pragma unroll
    for (int o = 0; o < 4; ++o){
      short8 b0 = *(const short8*)&Wl[(o*16 + n)*72 + q*8];
      short8 b1 = *(const short8*)&Wl[(o*16 + n)*72 + 32 + q*8];
      f32x4 c = {0.f, 0.f, 0.f, 0.f};
      c = __builtin_amdgcn_mfma_f32_16x16x32_bf16(a0, b0, c, 0, 0, 0);
      c = __builtin_amdgcn_mfma_f32_16x16x32_bf16(a1, b1, c, 0, 0, 0);
      #pragma unroll
      for (int r = 0; r < 4; ++r)
        Dbuf[(wv*16 + q*4 + r)*66 + o*16 + n] = c[r];
    }
  }
  __syncthreads();
  float gpw = pnw[lane], gpb = pnb[lane];
  float s1, s2;
  for (int i = 0; i < 16; ++i){
    int tl = wv*16 + i;
    size_t off = (size_t)(t0 + tl)*64 + lane;
    float v = Dbuf[tl*66 + lane];
    s1 = v; s2 = v*v;
    #pragma unroll
    for (int o2 = 32; o2 > 0; o2 >>= 1){ s1 += __shfl_xor(s1,o2,64); s2 += __shfl_xor(s2,o2,64); }
    float m = s1*(1.f/64.f);
    float qv = s2*(1.f/64.f) - m*m;
    float o = (v-m)*rsqrtf(qv+1e-5f)*gpw + gpb;
    o = nan2num(o, 0.f, 1.f, -1.f);
    float w = wg[off];
    float skip = nan2num(in0[off], 0.f, 1.f, -1.f);
    out[off] = fmaf(o, w, fmaf(x0n[off], 1.f - w, skip));
  }
}

// ================================================================ launcher
extern "C" void kernel_launch(void* const* d_in, const int* in_sizes, int n_in,
                              void* d_out, int out_size, void* d_ws, size_t ws_size,
                              hipStream_t stream)
{
  (void)in_sizes; (void)n_in; (void)out_size; (void)ws_size;
  const float* in0  = (const float*)d_in[0];
  const float* in1  = (const float*)d_in[1];
  const float* n0w  = (const float*)d_in[2];
  const float* n0b  = (const float*)d_in[3];
  const float* n1w  = (const float*)d_in[4];
  const float* n1b  = (const float*)d_in[5];
  const float* cww  = (const float*)d_in[6];
  const float* cwb  = (const float*)d_in[7];
  const float* cwnw = (const float*)d_in[8];
  const float* cwnb = (const float*)d_in[9];
  const float* ipw  = (const float*)d_in[10];
  const float* ipew = (const float*)d_in[11];
  const float* cwf  = (const float*)d_in[12];
  const float* cbf  = (const float*)d_in[13];
  const float* xpwf = (const float*)d_in[14];
  const float* dtwf = (const float*)d_in[15];
  const float* dtbf = (const float*)d_in[16];
  const float* Alf  = (const float*)d_in[17];
  const float* Dvf  = (const float*)d_in[18];
  const float* cwr  = (const float*)d_in[19];
  const float* cbr  = (const float*)d_in[20];
  const float* xpwr = (const float*)d_in[21];
  const float* dtwr = (const float*)d_in[22];
  const float* dtbr = (const float*)d_in[23];
  const float* Alr  = (const float*)d_in[24];
  const float* Dvr  = (const float*)d_in[25];
  const float* mnw  = (const float*)d_in[26];
  const float* opw  = (const float*)d_in[27];
  const float* pnw  = (const float*)d_in[28];
  const float* pnb  = (const float*)d_in[29];

  float* ws  = (float*)d_ws;
  float* x0n = ws + 0*EL;
  float* xa  = ws + 1*EL;   // conv input fwd; reused as yf
  float* xe  = ws + 2*EL;   // conv input rev; reused as yr
  float* uf  = ws + 3*EL;
  float* ur  = ws + 4*EL;
  float* wg  = ws + 5*EL;
  float* Bf  = ws + 6*EL;              // TOK*16 each (4 arrays = EL total)
  float* Cf  = Bf + (size_t)TOK*16;
  float* Br  = Cf + (size_t)TOK*16;
  float* Cr  = Br + (size_t)TOK*16;
  float* P   = ws + 7*EL;              // 2*TOK*16 floats = EL/2
  float* S   = P + 2*(size_t)TOK*16;   // EL/2
  unsigned short* zb  = (unsigned short*)(ws + 8*EL);
  unsigned short* zeb = zb + EL;
  float* dltf = ws + 9*EL;             // TOK*4 each
  float* dltr = dltf + (size_t)TOK*4;
  float* yfp = xa;
  float* yrp = xe;

  mega1<<<512, 256, 0, stream>>>(in0, in1, n0w, n0b, n1w, n1b, cww, cwb,
                                 cwnw, cwnb, ipw, ipew,
                                 x0n, wg, xa, xe, zb, zeb);
  g2_convproj<<<512, 256, 0, stream>>>(xa, xe, cwf, cbf, cwr, cbr,
                                       xpwf, xpwr,
                                       uf, ur, dltf, dltr, Bf, Cf, Br, Cr);
  k4a_scanA<<<1024, 256, 0, stream>>>(dltf, dltr, dtwf, dtbf, dtwr, dtbr,
                                      uf, ur, Bf, Br, Alf, Alr, P, S);
  k4b_ks<<<512, 256, 0, stream>>>(P, S);
  k4c_scanB<<<1024, 256, 0, stream>>>(dltf, dltr, dtwf, dtbf, dtwr, dtbr,
                                      uf, ur, Bf, Br, Cf, Cr,
                                      Alf, Alr, Dvf, Dvr, P, yfp, yrp);
  g3_post<<<1024, 256, 0, stream>>>(yfp, yrp, zb, zeb, wg, x0n, in0,
                                    mnw, opw, pnw, pnb, (float*)d_out);
}

// Round 7
// 344.081 us; speedup vs baseline: 1.1786x; 1.0513x over previous
//
#include <hip/hip_runtime.h>
#include <stdint.h>

#define BATCH 4
#define SEQL  16384
#define DIM   64
#define NST   16
#define TOK   (BATCH*SEQL)        /* 65536 tokens */
#define EL    ((size_t)TOK*DIM)   /* 4194304 elems per [B,L,D] array */
#define NCH   256                 /* chunks per (b,dir) */
#define CHL   64                  /* chunk length; NCH*CHL == SEQL */

typedef __attribute__((ext_vector_type(8))) short short8;
typedef __attribute__((ext_vector_type(4))) float f32x4;

__device__ __forceinline__ float nan2num(float x, float nv, float pv, float mv){
  if (__builtin_isnan(x)) return nv;
  if (__builtin_isinf(x)) return x > 0.f ? pv : mv;
  return x;
}
__device__ __forceinline__ float siluf(float x){ return x / (1.f + __expf(-x)); }
__device__ __forceinline__ float b2f(unsigned short s){
  union { unsigned u; float f; } v; v.u = ((unsigned)s) << 16; return v.f;
}
__device__ __forceinline__ unsigned short f2b(float f){
  union { float f; unsigned u; } v; v.f = f;
  unsigned r = v.u + 0x7fffu + ((v.u >> 16) & 1u);   // RNE
  return (unsigned short)(r >> 16);
}
// fast softplus: ln(1+e^x) = log2(1+2^(x*log2e))*ln2  (HW v_exp/v_log, no libm)
__device__ __forceinline__ float softplus_fast(float x){
  if (x > 20.f) return x;
  float t = exp2f(x * 1.44269504f);
  return __log2f(1.f + t) * 0.69314718f;
}

// ================================================================ MEGA1
__global__ __launch_bounds__(256) void mega1(
    const float* __restrict__ in0, const float* __restrict__ in1,
    const float* __restrict__ n0w, const float* __restrict__ n0b,
    const float* __restrict__ n1w, const float* __restrict__ n1b,
    const float* __restrict__ cww, const float* __restrict__ cwb,
    const float* __restrict__ cwnw, const float* __restrict__ cwnb,
    const float* __restrict__ ipw, const float* __restrict__ ipew,
    float* __restrict__ x0n, float* __restrict__ wg,
    float* __restrict__ xa,  float* __restrict__ xe,
    unsigned short* __restrict__ zb, unsigned short* __restrict__ zeb)
{
  __shared__ __align__(16) short Wl[192*72];
  __shared__ __align__(16) short Al[128*72];
  int tid = threadIdx.x;
  int t0 = blockIdx.x * 128;
  int lane = tid & 63, wv = tid >> 6;
  int n = lane & 15, q = lane >> 4;
  f32x4 wacc[2][4];

  #pragma unroll
  for (int s = 0; s < 2; ++s){
    const float* ips = s ? ipew : ipw;
    for (int sseg = tid; sseg < 192*8; sseg += 256){
      int row = sseg >> 3, sg = sseg & 7;
      const float* src = (row < 64) ? (cww + (size_t)row*128 + s*64 + sg*8)
                                    : (ips + (size_t)(row-64)*64 + sg*8);
      float4 f0 = ((const float4*)src)[0];
      float4 f1 = ((const float4*)src)[1];
      short8 v;
      v[0]=(short)f2b(f0.x); v[1]=(short)f2b(f0.y); v[2]=(short)f2b(f0.z); v[3]=(short)f2b(f0.w);
      v[4]=(short)f2b(f1.x); v[5]=(short)f2b(f1.y); v[6]=(short)f2b(f1.z); v[7]=(short)f2b(f1.w);
      *(short8*)&Wl[row*72 + sg*8] = v;
    }
    {
      const float* inp = s ? in1 : in0;
      const float* nw  = s ? n1w : n0w;
      const float* nb  = s ? n1b : n0b;
      int tl = tid >> 2, p = tid & 3;
      float gw[16], gb[16];
      #pragma unroll
      for (int i = 0; i < 4; ++i){
        float4 w4 = ((const float4*)(nw + p*16))[i];
        float4 b4 = ((const float4*)(nb + p*16))[i];
        gw[4*i]=w4.x; gw[4*i+1]=w4.y; gw[4*i+2]=w4.z; gw[4*i+3]=w4.w;
        gb[4*i]=b4.x; gb[4*i+1]=b4.y; gb[4*i+2]=b4.z; gb[4*i+3]=b4.w;
      }
      #pragma unroll
      for (int sp = 0; sp < 2; ++sp){
        int tok_l = sp*64 + tl;
        size_t ga = ((size_t)(t0 + tok_l))*64 + p*16;
        float v[16]; float s1 = 0.f, s2 = 0.f;
        #pragma unroll
        for (int i = 0; i < 4; ++i){
          float4 f = ((const float4*)(inp + ga))[i];
          float a0 = nan2num(f.x,0.f,1.f,-1.f), a1 = nan2num(f.y,0.f,1.f,-1.f);
          float a2 = nan2num(f.z,0.f,1.f,-1.f), a3 = nan2num(f.w,0.f,1.f,-1.f);
          v[4*i]=a0; v[4*i+1]=a1; v[4*i+2]=a2; v[4*i+3]=a3;
          s1 += a0+a1+a2+a3; s2 += a0*a0+a1*a1+a2*a2+a3*a3;
        }
        s1 += __shfl_xor(s1,1,64); s1 += __shfl_xor(s1,2,64);
        s2 += __shfl_xor(s2,1,64); s2 += __shfl_xor(s2,2,64);
        float m = s1*(1.f/64.f);
        float var = s2*(1.f/64.f) - m*m;
        float rs = rsqrtf(var + 1e-5f);
        float xr[16];
        #pragma unroll
        for (int i = 0; i < 16; ++i){
          float x = nan2num((v[i]-m)*rs*gw[i] + gb[i], 0.f, 1.f, -1.f);
          xr[i] = x;
          Al[tok_l*72 + p*16 + i] = (short)f2b(x);
        }
        if (s == 0){
          #pragma unroll
          for (int i = 0; i < 4; ++i)
            ((float4*)(x0n + ga))[i] = make_float4(xr[4*i],xr[4*i+1],xr[4*i+2],xr[4*i+3]);
        }
      }
    }
    __syncthreads();
    float* outx = s ? xe : xa;
    unsigned short* outz = s ? zeb : zb;
    #pragma unroll
    for (int mi = 0; mi < 2; ++mi){
      int mt = wv*2 + mi;
      short8 a0 = *(const short8*)&Al[(mt*16 + n)*72 + q*8];
      short8 a1 = *(const short8*)&Al[(mt*16 + n)*72 + 32 + q*8];
      #pragma unroll
      for (int o = 0; o < 12; ++o){
        short8 b0 = *(const short8*)&Wl[(o*16 + n)*72 + q*8];
        short8 b1 = *(const short8*)&Wl[(o*16 + n)*72 + 32 + q*8];
        f32x4 c = {0.f, 0.f, 0.f, 0.f};
        c = __builtin_amdgcn_mfma_f32_16x16x32_bf16(a0, b0, c, 0, 0, 0);
        c = __builtin_amdgcn_mfma_f32_16x16x32_bf16(a1, b1, c, 0, 0, 0);
        if (o < 4){
          if (s == 0) wacc[mi][o] = c; else wacc[mi][o] += c;
        } else if (o < 8){
          #pragma unroll
          for (int r = 0; r < 4; ++r)
            outx[((size_t)(t0 + mt*16 + q*4 + r))*64 + (o-4)*16 + n] = c[r];
        } else {
          #pragma unroll
          for (int r = 0; r < 4; ++r)
            outz[((size_t)(t0 + mt*16 + q*4 + r))*64 + (o-8)*16 + n] = f2b(c[r]);
        }
      }
    }
    if (s == 0) __syncthreads();
  }
  float cb_l[4], gnw[4], gnb[4];
  #pragma unroll
  for (int o = 0; o < 4; ++o){
    cb_l[o] = cwb[o*16+n]; gnw[o] = cwnw[o*16+n]; gnb[o] = cwnb[o*16+n];
  }
  #pragma unroll
  for (int mi = 0; mi < 2; ++mi){
    #pragma unroll
    for (int r = 0; r < 4; ++r){
      float v[4]; float sv = 0.f, sq = 0.f;
      #pragma unroll
      for (int o = 0; o < 4; ++o){
        v[o] = wacc[mi][o][r] + cb_l[o];
        sv += v[o]; sq += v[o]*v[o];
      }
      sv += __shfl_xor(sv,1,64); sv += __shfl_xor(sv,2,64);
      sv += __shfl_xor(sv,4,64); sv += __shfl_xor(sv,8,64);
      sq += __shfl_xor(sq,1,64); sq += __shfl_xor(sq,2,64);
      sq += __shfl_xor(sq,4,64); sq += __shfl_xor(sq,8,64);
      float m = sv*(1.f/64.f);
      float var = sq*(1.f/64.f) - m*m;
      float rs = rsqrtf(var + 1e-5f);
      size_t tok = (size_t)t0 + (wv*2+mi)*16 + q*4 + r;
      #pragma unroll
      for (int o = 0; o < 4; ++o){
        float wn = (v[o]-m)*rs*gnw[o] + gnb[o];
        wn = nan2num(wn, 0.5f, 1.f, 0.f);
        wn = 1.f/(1.f + __expf(-wn));
        wn = fminf(fmaxf(wn, 0.01f), 0.99f);
        wg[tok*64 + o*16 + n] = wn;
      }
    }
  }
}

// ================================================================ G2: conv + xproj
__global__ __launch_bounds__(256) void g2_convproj(
    const float* __restrict__ xa, const float* __restrict__ xe,
    const float* __restrict__ cwf, const float* __restrict__ cbf,
    const float* __restrict__ cwr, const float* __restrict__ cbr,
    const float* __restrict__ xpwf, const float* __restrict__ xpwr,
    float* __restrict__ uf, float* __restrict__ ur,
    float* __restrict__ dltf, float* __restrict__ dltr,
    float* __restrict__ Bf, float* __restrict__ Cf,
    float* __restrict__ Br, float* __restrict__ Cr)
{
  __shared__ __align__(16) short Wl[2*48*72];
  __shared__ __align__(16) short Al[2*128*72];
  int tid = threadIdx.x;
  int b = blockIdx.x >> 7, l0 = (blockIdx.x & 127) * 128;
  size_t base = (size_t)b * SEQL;
  for (int sseg = tid; sseg < 2*48*8; sseg += 256){
    int s = sseg >= 48*8;
    int rs = sseg - s*48*8;
    int row = rs >> 3, sg = rs & 7;
    const float* xp = s ? xpwr : xpwf;
    short8 v = {0,0,0,0,0,0,0,0};
    int srcrow = (row < 32) ? (4+row) : (row < 36) ? (row-32) : -1;
    if (srcrow >= 0){
      const float* src = xp + (size_t)srcrow*64 + sg*8;
      float4 f0 = ((const float4*)src)[0];
      float4 f1 = ((const float4*)src)[1];
      v[0]=(short)f2b(f0.x); v[1]=(short)f2b(f0.y); v[2]=(short)f2b(f0.z); v[3]=(short)f2b(f0.w);
      v[4]=(short)f2b(f1.x); v[5]=(short)f2b(f1.y); v[6]=(short)f2b(f1.z); v[7]=(short)f2b(f1.w);
    }
    *(short8*)&Wl[(s*48+row)*72 + sg*8] = v;
  }
  {
    int d = tid & 63, lq = tid >> 6;
    float4 wf4 = ((const float4*)cwf)[d];
    float4 wr4 = ((const float4*)cwr)[d];
    float bf = cbf[d], brr = cbr[d];
    for (int i = 0; i < 8; ++i){
      int ll = i*16 + lq*4;
      int gl = l0 + ll;
      float rv[7], sv[7];
      #pragma unroll
      for (int j = 0; j < 7; ++j){
        int li = gl - 3 + j;
        rv[j] = (li >= 0) ? xa[(base + li)*64 + d] : 0.f;
        int lj = gl + j;
        sv[j] = (lj < SEQL) ? xe[(base + lj)*64 + d] : 0.f;
      }
      #pragma unroll
      for (int k = 0; k < 4; ++k){
        float a = bf + wf4.x*rv[k] + wf4.y*rv[k+1] + wf4.z*rv[k+2] + wf4.w*rv[k+3];
        a = siluf(a);
        uf[(base + gl + k)*64 + d] = a;
        Al[(ll+k)*72 + d] = (short)f2b(a);
        float r = brr + wr4.w*sv[k] + wr4.z*sv[k+1] + wr4.y*sv[k+2] + wr4.x*sv[k+3];
        r = siluf(r);
        ur[(base + gl + k)*64 + d] = r;
        Al[(128 + ll + k)*72 + d] = (short)f2b(r);
      }
    }
  }
  __syncthreads();
  int lane = tid & 63, wv = tid >> 6;
  int n = lane & 15, q = lane >> 4;
  #pragma unroll
  for (int s = 0; s < 2; ++s){
    const short* As = &Al[s*128*72];
    const short* Ws = &Wl[s*48*72];
    float* Bo = s ? Br : Bf;
    float* Co = s ? Cr : Cf;
    float* Do = s ? dltr : dltf;
    #pragma unroll
    for (int mi = 0; mi < 2; ++mi){
      int mt = wv*2 + mi;
      short8 a0 = *(const short8*)&As[(mt*16 + n)*72 + q*8];
      short8 a1 = *(const short8*)&As[(mt*16 + n)*72 + 32 + q*8];
      f32x4 acc[3];
      #pragma unroll
      for (int o = 0; o < 3; ++o){
        short8 b0 = *(const short8*)&Ws[(o*16 + n)*72 + q*8];
        short8 b1 = *(const short8*)&Ws[(o*16 + n)*72 + 32 + q*8];
        f32x4 c = {0.f, 0.f, 0.f, 0.f};
        c = __builtin_amdgcn_mfma_f32_16x16x32_bf16(a0, b0, c, 0, 0, 0);
        c = __builtin_amdgcn_mfma_f32_16x16x32_bf16(a1, b1, c, 0, 0, 0);
        acc[o] = c;
      }
      #pragma unroll
      for (int r = 0; r < 4; ++r){
        size_t tok = base + l0 + mt*16 + q*4 + r;
        Bo[tok*16 + n] = acc[0][r];
        Co[tok*16 + n] = acc[1][r];
        if (n < 4) Do[tok*4 + n] = acc[2][r];
      }
    }
  }
}

// ================================================================ K4a: chunk compose (LDS-staged)
// block per (b,dir,chunk); thread = (d = wv*16+(lane&15), nq = lane>>4), 4 states.
__global__ __launch_bounds__(256) void k4a_scanA(
    const float* __restrict__ dltf, const float* __restrict__ dltr,
    const float* __restrict__ dtwf, const float* __restrict__ dtbf,
    const float* __restrict__ dtwr, const float* __restrict__ dtbr,
    const float* __restrict__ uf,  const float* __restrict__ ur,
    const float* __restrict__ Bf,  const float* __restrict__ Br,
    const float* __restrict__ Alf, const float* __restrict__ Alr,
    float* __restrict__ P, float* __restrict__ S)
{
  __shared__ float sDt[64*64];
  __shared__ float sU[64*64];
  __shared__ float sB[64*16];
  int tid = threadIdx.x;
  int bx = blockIdx.x;
  int c = bx & (NCH-1), dir = (bx >> 8) & 1, b = bx >> 9;
  const float* dlt = dir ? dltr : dltf;
  const float* u   = dir ? ur  : uf;
  const float* Bm  = dir ? Br  : Bf;
  const float* Al  = dir ? Alr : Alf;
  const float* dtw = dir ? dtwr : dtwf;
  const float* dtb = dir ? dtbr : dtbf;
  size_t t0 = (size_t)b*SEQL + (dir ? (SEQL - (size_t)(c+1)*CHL) : (size_t)c*CHL);
  // ---- stage u (4096 floats) and B (1024 floats), contiguous
  {
    const float4* gu = (const float4*)(u + t0*64);
    #pragma unroll
    for (int i = 0; i < 4; ++i)
      ((float4*)sU)[tid + i*256] = gu[tid + i*256];
    const float4* gB = (const float4*)(Bm + t0*16);
    ((float4*)sB)[tid] = gB[tid];
  }
  // ---- compute dt tile: thread (d = tid&63, lq = tid>>6) does 16 l's
  {
    int d = tid & 63, lq = tid >> 6;
    float4 wd = ((const float4*)dtw)[d];
    float bd = dtb[d];
    #pragma unroll 4
    for (int k = 0; k < 16; ++k){
      int l = lq*16 + k;
      float4 dl = *(const float4*)(dlt + (t0 + l)*4);
      sDt[l*64 + d] = softplus_fast(fmaf(wd.x,dl.x, fmaf(wd.y,dl.y,
                                    fmaf(wd.z,dl.z, fmaf(wd.w,dl.w, bd)))));
    }
  }
  __syncthreads();
  // ---- scan out of LDS
  int lane = tid & 63, wv = tid >> 6;
  int nq = lane >> 4;
  int d = wv*16 + (lane & 15);
  float A2[4], Pp[4] = {1.f,1.f,1.f,1.f}, Ss[4] = {0.f,0.f,0.f,0.f};
  #pragma unroll
  for (int j = 0; j < 4; ++j)
    A2[j] = -__expf(Al[d*16 + nq*4 + j]) * 1.44269504f;
  for (int i = 0; i < CHL; ++i){
    int li = dir ? (CHL-1-i) : i;
    float dtv = sDt[li*64 + d];
    float uv  = sU[li*64 + d];
    float4 b4 = *(const float4*)&sB[li*16 + nq*4];
    float du = dtv * uv;
    float bb[4] = {b4.x, b4.y, b4.z, b4.w};
    #pragma unroll
    for (int j = 0; j < 4; ++j){
      float a = exp2f(dtv*A2[j]);
      Pp[j] *= a;
      Ss[j] = fmaf(a, Ss[j], du*bb[j]);
    }
  }
  size_t pidx = (((size_t)(b*2+dir)*NCH + c)*64 + d)*16 + nq*4;
  *(float4*)(P + pidx) = make_float4(Pp[0],Pp[1],Pp[2],Pp[3]);
  *(float4*)(S + pidx) = make_float4(Ss[0],Ss[1],Ss[2],Ss[3]);
}

// ================================================================ K4b: Kogge-Stone carry scan
__global__ __launch_bounds__(256) void k4b_ks(float* __restrict__ P,
                                              const float* __restrict__ S)
{
  __shared__ float Pl[256*18], Sl[256*18];
  int c = threadIdx.x;
  int d = blockIdx.x & 63, bd = blockIdx.x >> 6;
  size_t idx = (((size_t)bd*NCH + c)*64 + d)*16;
  float p[16], s[16];
  #pragma unroll
  for (int k = 0; k < 4; k++){
    float4 pv = ((const float4*)(P + idx))[k];
    float4 sv = ((const float4*)(S + idx))[k];
    p[4*k]=pv.x; p[4*k+1]=pv.y; p[4*k+2]=pv.z; p[4*k+3]=pv.w;
    s[4*k]=sv.x; s[4*k+1]=sv.y; s[4*k+2]=sv.z; s[4*k+3]=sv.w;
  }
  #pragma unroll
  for (int j = 0; j < 8; j++){
    *(float2*)&Pl[c*18 + 2*j] = make_float2(p[2*j], p[2*j+1]);
    *(float2*)&Sl[c*18 + 2*j] = make_float2(s[2*j], s[2*j+1]);
  }
  for (int step = 1; step < NCH; step <<= 1){
    __syncthreads();
    float pp[16], ss[16];
    bool act = (c >= step);
    if (act){
      #pragma unroll
      for (int j = 0; j < 8; j++){
        float2 tp = *(const float2*)&Pl[(c-step)*18 + 2*j];
        float2 ts = *(const float2*)&Sl[(c-step)*18 + 2*j];
        pp[2*j]=tp.x; pp[2*j+1]=tp.y; ss[2*j]=ts.x; ss[2*j+1]=ts.y;
      }
    }
    __syncthreads();
    if (act){
      #pragma unroll
      for (int n = 0; n < 16; n++){
        s[n] = fmaf(p[n], ss[n], s[n]);
        p[n] *= pp[n];
      }
      #pragma unroll
      for (int j = 0; j < 8; j++){
        *(float2*)&Pl[c*18 + 2*j] = make_float2(p[2*j], p[2*j+1]);
        *(float2*)&Sl[c*18 + 2*j] = make_float2(s[2*j], s[2*j+1]);
      }
    }
  }
  __syncthreads();
  float ho[16];
  if (c == 0){
    #pragma unroll
    for (int n = 0; n < 16; n++) ho[n] = 0.f;
  } else {
    #pragma unroll
    for (int j = 0; j < 8; j++){
      float2 ts = *(const float2*)&Sl[(c-1)*18 + 2*j];
      ho[2*j]=ts.x; ho[2*j+1]=ts.y;
    }
  }
  #pragma unroll
  for (int k = 0; k < 4; k++)
    ((float4*)(P + idx))[k] = make_float4(ho[4*k], ho[4*k+1], ho[4*k+2], ho[4*k+3]);
}

// ================================================================ K4c: scan pass B (LDS-staged)
// block per (b,dir,chunk); y accumulated in LDS tile, bulk-written.
__global__ __launch_bounds__(256) void k4c_scanB(
    const float* __restrict__ dltf, const float* __restrict__ dltr,
    const float* __restrict__ dtwf, const float* __restrict__ dtbf,
    const float* __restrict__ dtwr, const float* __restrict__ dtbr,
    const float* __restrict__ uf,  const float* __restrict__ ur,
    const float* __restrict__ Bf,  const float* __restrict__ Br,
    const float* __restrict__ Cf,  const float* __restrict__ Cr,
    const float* __restrict__ Alf, const float* __restrict__ Alr,
    const float* __restrict__ Dvf, const float* __restrict__ Dvr,
    const float* __restrict__ Hpre, float* __restrict__ yf, float* __restrict__ yr)
{
  __shared__ float sDt[64*64];
  __shared__ float sDu[64*64];   // staged raw u, converted to dt*u
  __shared__ float sB[64*16];
  __shared__ float sC[64*16];
  __shared__ float sY[64*64];
  int tid = threadIdx.x;
  int bx = blockIdx.x;
  int c = bx & (NCH-1), dir = (bx >> 8) & 1, b = bx >> 9;
  const float* dlt = dir ? dltr : dltf;
  const float* u   = dir ? ur  : uf;
  const float* Bm  = dir ? Br  : Bf;
  const float* Cm  = dir ? Cr  : Cf;
  const float* Al  = dir ? Alr : Alf;
  const float* dtw = dir ? dtwr : dtwf;
  const float* dtb = dir ? dtbr : dtbf;
  const float* Dv  = dir ? Dvr : Dvf;
  float* y = dir ? yr : yf;
  size_t t0 = (size_t)b*SEQL + (dir ? (SEQL - (size_t)(c+1)*CHL) : (size_t)c*CHL);
  // ---- stage raw u, B, C
  {
    const float4* gu = (const float4*)(u + t0*64);
    #pragma unroll
    for (int i = 0; i < 4; ++i)
      ((float4*)sDu)[tid + i*256] = gu[tid + i*256];
    const float4* gB = (const float4*)(Bm + t0*16);
    ((float4*)sB)[tid] = gB[tid];
    const float4* gC = (const float4*)(Cm + t0*16);
    ((float4*)sC)[tid] = gC[tid];
  }
  // ---- dt tile
  {
    int d = tid & 63, lq = tid >> 6;
    float4 wd = ((const float4*)dtw)[d];
    float bd = dtb[d];
    #pragma unroll 4
    for (int k = 0; k < 16; ++k){
      int l = lq*16 + k;
      float4 dl = *(const float4*)(dlt + (t0 + l)*4);
      sDt[l*64 + d] = softplus_fast(fmaf(wd.x,dl.x, fmaf(wd.y,dl.y,
                                    fmaf(wd.z,dl.z, fmaf(wd.w,dl.w, bd)))));
    }
  }
  __syncthreads();
  // ---- convert: sY = u*Dd; sDu = dt*u
  {
    int d = tid & 63, lq = tid >> 6;
    float Dd = Dv[d];
    #pragma unroll 4
    for (int k = 0; k < 16; ++k){
      int l = lq*16 + k;
      float uv = sDu[l*64 + d];
      sY[l*64 + d] = uv * Dd;
      sDu[l*64 + d] = sDt[l*64 + d] * uv;
    }
  }
  __syncthreads();
  // ---- scan out of LDS
  int lane = tid & 63, wv = tid >> 6;
  int nq = lane >> 4;
  int d = wv*16 + (lane & 15);
  float A2[4], h[4];
  #pragma unroll
  for (int j = 0; j < 4; ++j)
    A2[j] = -__expf(Al[d*16 + nq*4 + j]) * 1.44269504f;
  size_t pidx = (((size_t)(b*2+dir)*NCH + c)*64 + d)*16 + nq*4;
  float4 h4 = *(const float4*)(Hpre + pidx);
  h[0]=h4.x; h[1]=h4.y; h[2]=h4.z; h[3]=h4.w;
  for (int i = 0; i < CHL; ++i){
    int li = dir ? (CHL-1-i) : i;
    float dtv = sDt[li*64 + d];
    float du  = sDu[li*64 + d];
    float4 b4 = *(const float4*)&sB[li*16 + nq*4];
    float4 c4 = *(const float4*)&sC[li*16 + nq*4];
    float bb[4] = {b4.x, b4.y, b4.z, b4.w};
    float cc[4] = {c4.x, c4.y, c4.z, c4.w};
    float yv = 0.f;
    #pragma unroll
    for (int j = 0; j < 4; ++j){
      float a = exp2f(dtv*A2[j]);
      h[j] = fmaf(a, h[j], du*bb[j]);
      yv = fmaf(h[j], cc[j], yv);
    }
    yv += __shfl_xor(yv, 16, 64);
    yv += __shfl_xor(yv, 32, 64);
    if (nq == 0) sY[li*64 + d] += yv;
  }
  __syncthreads();
  // ---- bulk write y
  {
    float4* gy = (float4*)(y + t0*64);
    #pragma unroll
    for (int i = 0; i < 4; ++i)
      gy[tid + i*256] = ((const float4*)sY)[tid + i*256];
  }
}

// ================================================================ G3: epilogue
__global__ __launch_bounds__(256) void g3_post(
    const float* __restrict__ yf, const float* __restrict__ yr,
    const unsigned short* __restrict__ zb, const unsigned short* __restrict__ zeb,
    const float* __restrict__ wg, const float* __restrict__ x0n,
    const float* __restrict__ in0,
    const float* __restrict__ mnw, const float* __restrict__ opw,
    const float* __restrict__ pnw, const float* __restrict__ pnb,
    float* __restrict__ out)
{
  __shared__ __align__(16) short Wl[64*72];
  __shared__ __align__(16) short Al[64*72];
  __shared__ float Dbuf[64*66];
  int tid = threadIdx.x;
  int t0 = blockIdx.x * 64;
  for (int sseg = tid; sseg < 64*8; sseg += 256){
    int row = sseg >> 3, sg = sseg & 7;
    const float* src = opw + (size_t)row*64 + sg*8;
    float4 f0 = ((const float4*)src)[0];
    float4 f1 = ((const float4*)src)[1];
    short8 v;
    v[0]=(short)f2b(f0.x); v[1]=(short)f2b(f0.y); v[2]=(short)f2b(f0.z); v[3]=(short)f2b(f0.w);
    v[4]=(short)f2b(f1.x); v[5]=(short)f2b(f1.y); v[6]=(short)f2b(f1.z); v[7]=(short)f2b(f1.w);
    *(short8*)&Wl[row*72 + sg*8] = v;
  }
  {
    int tl = tid >> 2, p = tid & 3;
    size_t g = (size_t)(t0 + tl)*64 + p*16;
    float4 yf4[4], yr4[4];
    #pragma unroll
    for (int i = 0; i < 4; i++){
      yf4[i] = ((const float4*)(yf + g))[i];
      yr4[i] = ((const float4*)(yr + g))[i];
    }
    short8 z8a  = *(const short8*)(zb + g);
    short8 z8b  = *(const short8*)(zb + g + 8);
    short8 ze8a = *(const short8*)(zeb + g);
    short8 ze8b = *(const short8*)(zeb + g + 8);
    float vy[16]; float ss = 0.f;
    #pragma unroll
    for (int i = 0; i < 16; i++){
      float yfv = ((const float*)yf4)[i];
      float yrv = ((const float*)yr4)[i];
      float zv  = b2f((unsigned short)(i < 8 ? z8a[i] : z8b[i-8]));
      float zev = b2f((unsigned short)(i < 8 ? ze8a[i] : ze8b[i-8]));
      float v = 0.5f*(yfv*siluf(zv) + yrv*siluf(zev));
      vy[i] = v; ss += v*v;
    }
    ss += __shfl_xor(ss, 1, 64);
    ss += __shfl_xor(ss, 2, 64);
    float rms = rsqrtf(ss*(1.f/64.f) + 1e-5f);
    #pragma unroll
    for (int i = 0; i < 16; i++){
      float w = mnw[p*16 + i];
      Al[tl*72 + p*16 + i] = (short)f2b(vy[i]*rms*w);
    }
  }
  __syncthreads();
  int lane = tid & 63, wv = tid >> 6;
  int n = lane & 15, q = lane >> 4;
  {
    short8 a0 = *(const short8*)&Al[(wv*16 + n)*72 + q*8];
    short8 a1 = *(const short8*)&Al[(wv*16 + n)*72 + 32 + q*8];
    #pragma unroll
    for (int o = 0; o < 4; ++o){
      short8 b0 = *(const short8*)&Wl[(o*16 + n)*72 + q*8];
      short8 b1 = *(const short8*)&Wl[(o*16 + n)*72 + 32 + q*8];
      f32x4 c = {0.f, 0.f, 0.f, 0.f};
      c = __builtin_amdgcn_mfma_f32_16x16x32_bf16(a0, b0, c, 0, 0, 0);
      c = __builtin_amdgcn_mfma_f32_16x16x32_bf16(a1, b1, c, 0, 0, 0);
      #pragma unroll
      for (int r = 0; r < 4; ++r)
        Dbuf[(wv*16 + q*4 + r)*66 + o*16 + n] = c[r];
    }
  }
  __syncthreads();
  float gpw = pnw[lane], gpb = pnb[lane];
  float s1, s2;
  for (int i = 0; i < 16; ++i){
    int tl = wv*16 + i;
    size_t off = (size_t)(t0 + tl)*64 + lane;
    float v = Dbuf[tl*66 + lane];
    s1 = v; s2 = v*v;
    #pragma unroll
    for (int o2 = 32; o2 > 0; o2 >>= 1){ s1 += __shfl_xor(s1,o2,64); s2 += __shfl_xor(s2,o2,64); }
    float m = s1*(1.f/64.f);
    float qv = s2*(1.f/64.f) - m*m;
    float o = (v-m)*rsqrtf(qv+1e-5f)*gpw + gpb;
    o = nan2num(o, 0.f, 1.f, -1.f);
    float w = wg[off];
    float skip = nan2num(in0[off], 0.f, 1.f, -1.f);
    out[off] = fmaf(o, w, fmaf(x0n[off], 1.f - w, skip));
  }
}

// ================================================================ launcher
extern "C" void kernel_launch(void* const* d_in, const int* in_sizes, int n_in,
                              void* d_out, int out_size, void* d_ws, size_t ws_size,
                              hipStream_t stream)
{
  (void)in_sizes; (void)n_in; (void)out_size; (void)ws_size;
  const float* in0  = (const float*)d_in[0];
  const float* in1  = (const float*)d_in[1];
  const float* n0w  = (const float*)d_in[2];
  const float* n0b  = (const float*)d_in[3];
  const float* n1w  = (const float*)d_in[4];
  const float* n1b  = (const float*)d_in[5];
  const float* cww  = (const float*)d_in[6];
  const float* cwb  = (const float*)d_in[7];
  const float* cwnw = (const float*)d_in[8];
  const float* cwnb = (const float*)d_in[9];
  const float* ipw  = (const float*)d_in[10];
  const float* ipew = (const float*)d_in[11];
  const float* cwf  = (const float*)d_in[12];
  const float* cbf  = (const float*)d_in[13];
  const float* xpwf = (const float*)d_in[14];
  const float* dtwf = (const float*)d_in[15];
  const float* dtbf = (const float*)d_in[16];
  const float* Alf  = (const float*)d_in[17];
  const float* Dvf  = (const float*)d_in[18];
  const float* cwr  = (const float*)d_in[19];
  const float* cbr  = (const float*)d_in[20];
  const float* xpwr = (const float*)d_in[21];
  const float* dtwr = (const float*)d_in[22];
  const float* dtbr = (const float*)d_in[23];
  const float* Alr  = (const float*)d_in[24];
  const float* Dvr  = (const float*)d_in[25];
  const float* mnw  = (const float*)d_in[26];
  const float* opw  = (const float*)d_in[27];
  const float* pnw  = (const float*)d_in[28];
  const float* pnb  = (const float*)d_in[29];

  float* ws  = (float*)d_ws;
  float* x0n = ws + 0*EL;
  float* xa  = ws + 1*EL;   // conv input fwd; reused as yf
  float* xe  = ws + 2*EL;   // conv input rev; reused as yr
  float* uf  = ws + 3*EL;
  float* ur  = ws + 4*EL;
  float* wg  = ws + 5*EL;
  float* Bf  = ws + 6*EL;              // TOK*16 each (4 arrays = EL total)
  float* Cf  = Bf + (size_t)TOK*16;
  float* Br  = Cf + (size_t)TOK*16;
  float* Cr  = Br + (size_t)TOK*16;
  float* P   = ws + 7*EL;              // 2*TOK*16 floats = EL/2
  float* S   = P + 2*(size_t)TOK*16;   // EL/2
  unsigned short* zb  = (unsigned short*)(ws + 8*EL);
  unsigned short* zeb = zb + EL;
  float* dltf = ws + 9*EL;             // TOK*4 each
  float* dltr = dltf + (size_t)TOK*4;
  float* yfp = xa;
  float* yrp = xe;

  mega1<<<512, 256, 0, stream>>>(in0, in1, n0w, n0b, n1w, n1b, cww, cwb,
                                 cwnw, cwnb, ipw, ipew,
                                 x0n, wg, xa, xe, zb, zeb);
  g2_convproj<<<512, 256, 0, stream>>>(xa, xe, cwf, cbf, cwr, cbr,
                                       xpwf, xpwr,
                                       uf, ur, dltf, dltr, Bf, Cf, Br, Cr);
  k4a_scanA<<<2048, 256, 0, stream>>>(dltf, dltr, dtwf, dtbf, dtwr, dtbr,
                                      uf, ur, Bf, Br, Alf, Alr, P, S);
  k4b_ks<<<512, 256, 0, stream>>>(P, S);
  k4c_scanB<<<2048, 256, 0, stream>>>(dltf, dltr, dtwf, dtbf, dtwr, dtbr,
                                      uf, ur, Bf, Br, Cf, Cr,
                                      Alf, Alr, Dvf, Dvr, P, yfp, yrp);
  g3_post<<<1024, 256, 0, stream>>>(yfp, yrp, zb, zeb, wg, x0n, in0,
                                    mnw, opw, pnw, pnb, (float*)d_out);
}

// Round 8
// 336.432 us; speedup vs baseline: 1.2054x; 1.0227x over previous
//
#include <hip/hip_runtime.h>
#include <stdint.h>

#define BATCH 4
#define SEQL  16384
#define DIM   64
#define NST   16
#define TOK   (BATCH*SEQL)        /* 65536 tokens */
#define EL    ((size_t)TOK*DIM)   /* 4194304 elems per [B,L,D] array */
#define NCH   256                 /* chunks per (b,dir) */
#define CHL   64                  /* chunk length; NCH*CHL == SEQL */

typedef __attribute__((ext_vector_type(8))) short short8;
typedef __attribute__((ext_vector_type(4))) float f32x4;

__device__ __forceinline__ float nan2num(float x, float nv, float pv, float mv){
  if (__builtin_isnan(x)) return nv;
  if (__builtin_isinf(x)) return x > 0.f ? pv : mv;
  return x;
}
__device__ __forceinline__ float siluf(float x){ return x / (1.f + __expf(-x)); }
__device__ __forceinline__ float b2f(unsigned short s){
  union { unsigned u; float f; } v; v.u = ((unsigned)s) << 16; return v.f;
}
__device__ __forceinline__ unsigned short f2b(float f){
  union { float f; unsigned u; } v; v.f = f;
  unsigned r = v.u + 0x7fffu + ((v.u >> 16) & 1u);   // RNE
  return (unsigned short)(r >> 16);
}
// fast softplus: ln(1+e^x) = log2(1+2^(x*log2e))*ln2  (HW v_exp/v_log, no libm)
__device__ __forceinline__ float softplus_fast(float x){
  if (x > 20.f) return x;
  float t = exp2f(x * 1.44269504f);
  return __log2f(1.f + t) * 0.69314718f;
}

// ================================================================ MEGA1
__global__ __launch_bounds__(256) void mega1(
    const float* __restrict__ in0, const float* __restrict__ in1,
    const float* __restrict__ n0w, const float* __restrict__ n0b,
    const float* __restrict__ n1w, const float* __restrict__ n1b,
    const float* __restrict__ cww, const float* __restrict__ cwb,
    const float* __restrict__ cwnw, const float* __restrict__ cwnb,
    const float* __restrict__ ipw, const float* __restrict__ ipew,
    float* __restrict__ x0n, float* __restrict__ wg,
    float* __restrict__ xa,  float* __restrict__ xe,
    unsigned short* __restrict__ zb, unsigned short* __restrict__ zeb)
{
  __shared__ __align__(16) short Wl[192*72];
  __shared__ __align__(16) short Al[128*72];
  int tid = threadIdx.x;
  int t0 = blockIdx.x * 128;
  int lane = tid & 63, wv = tid >> 6;
  int n = lane & 15, q = lane >> 4;
  f32x4 wacc[2][4];

  #pragma unroll
  for (int s = 0; s < 2; ++s){
    const float* ips = s ? ipew : ipw;
    for (int sseg = tid; sseg < 192*8; sseg += 256){
      int row = sseg >> 3, sg = sseg & 7;
      const float* src = (row < 64) ? (cww + (size_t)row*128 + s*64 + sg*8)
                                    : (ips + (size_t)(row-64)*64 + sg*8);
      float4 f0 = ((const float4*)src)[0];
      float4 f1 = ((const float4*)src)[1];
      short8 v;
      v[0]=(short)f2b(f0.x); v[1]=(short)f2b(f0.y); v[2]=(short)f2b(f0.z); v[3]=(short)f2b(f0.w);
      v[4]=(short)f2b(f1.x); v[5]=(short)f2b(f1.y); v[6]=(short)f2b(f1.z); v[7]=(short)f2b(f1.w);
      *(short8*)&Wl[row*72 + sg*8] = v;
    }
    {
      const float* inp = s ? in1 : in0;
      const float* nw  = s ? n1w : n0w;
      const float* nb  = s ? n1b : n0b;
      int tl = tid >> 2, p = tid & 3;
      float gw[16], gb[16];
      #pragma unroll
      for (int i = 0; i < 4; ++i){
        float4 w4 = ((const float4*)(nw + p*16))[i];
        float4 b4 = ((const float4*)(nb + p*16))[i];
        gw[4*i]=w4.x; gw[4*i+1]=w4.y; gw[4*i+2]=w4.z; gw[4*i+3]=w4.w;
        gb[4*i]=b4.x; gb[4*i+1]=b4.y; gb[4*i+2]=b4.z; gb[4*i+3]=b4.w;
      }
      #pragma unroll
      for (int sp = 0; sp < 2; ++sp){
        int tok_l = sp*64 + tl;
        size_t ga = ((size_t)(t0 + tok_l))*64 + p*16;
        float v[16]; float s1 = 0.f, s2 = 0.f;
        #pragma unroll
        for (int i = 0; i < 4; ++i){
          float4 f = ((const float4*)(inp + ga))[i];
          float a0 = nan2num(f.x,0.f,1.f,-1.f), a1 = nan2num(f.y,0.f,1.f,-1.f);
          float a2 = nan2num(f.z,0.f,1.f,-1.f), a3 = nan2num(f.w,0.f,1.f,-1.f);
          v[4*i]=a0; v[4*i+1]=a1; v[4*i+2]=a2; v[4*i+3]=a3;
          s1 += a0+a1+a2+a3; s2 += a0*a0+a1*a1+a2*a2+a3*a3;
        }
        s1 += __shfl_xor(s1,1,64); s1 += __shfl_xor(s1,2,64);
        s2 += __shfl_xor(s2,1,64); s2 += __shfl_xor(s2,2,64);
        float m = s1*(1.f/64.f);
        float var = s2*(1.f/64.f) - m*m;
        float rs = rsqrtf(var + 1e-5f);
        float xr[16];
        #pragma unroll
        for (int i = 0; i < 16; ++i){
          float x = nan2num((v[i]-m)*rs*gw[i] + gb[i], 0.f, 1.f, -1.f);
          xr[i] = x;
          Al[tok_l*72 + p*16 + i] = (short)f2b(x);
        }
        if (s == 0){
          #pragma unroll
          for (int i = 0; i < 4; ++i)
            ((float4*)(x0n + ga))[i] = make_float4(xr[4*i],xr[4*i+1],xr[4*i+2],xr[4*i+3]);
        }
      }
    }
    __syncthreads();
    float* outx = s ? xe : xa;
    unsigned short* outz = s ? zeb : zb;
    #pragma unroll
    for (int mi = 0; mi < 2; ++mi){
      int mt = wv*2 + mi;
      short8 a0 = *(const short8*)&Al[(mt*16 + n)*72 + q*8];
      short8 a1 = *(const short8*)&Al[(mt*16 + n)*72 + 32 + q*8];
      #pragma unroll
      for (int o = 0; o < 12; ++o){
        short8 b0 = *(const short8*)&Wl[(o*16 + n)*72 + q*8];
        short8 b1 = *(const short8*)&Wl[(o*16 + n)*72 + 32 + q*8];
        f32x4 c = {0.f, 0.f, 0.f, 0.f};
        c = __builtin_amdgcn_mfma_f32_16x16x32_bf16(a0, b0, c, 0, 0, 0);
        c = __builtin_amdgcn_mfma_f32_16x16x32_bf16(a1, b1, c, 0, 0, 0);
        if (o < 4){
          if (s == 0) wacc[mi][o] = c; else wacc[mi][o] += c;
        } else if (o < 8){
          #pragma unroll
          for (int r = 0; r < 4; ++r)
            outx[((size_t)(t0 + mt*16 + q*4 + r))*64 + (o-4)*16 + n] = c[r];
        } else {
          #pragma unroll
          for (int r = 0; r < 4; ++r)
            outz[((size_t)(t0 + mt*16 + q*4 + r))*64 + (o-8)*16 + n] = f2b(c[r]);
        }
      }
    }
    if (s == 0) __syncthreads();
  }
  float cb_l[4], gnw[4], gnb[4];
  #pragma unroll
  for (int o = 0; o < 4; ++o){
    cb_l[o] = cwb[o*16+n]; gnw[o] = cwnw[o*16+n]; gnb[o] = cwnb[o*16+n];
  }
  #pragma unroll
  for (int mi = 0; mi < 2; ++mi){
    #pragma unroll
    for (int r = 0; r < 4; ++r){
      float v[4]; float sv = 0.f, sq = 0.f;
      #pragma unroll
      for (int o = 0; o < 4; ++o){
        v[o] = wacc[mi][o][r] + cb_l[o];
        sv += v[o]; sq += v[o]*v[o];
      }
      sv += __shfl_xor(sv,1,64); sv += __shfl_xor(sv,2,64);
      sv += __shfl_xor(sv,4,64); sv += __shfl_xor(sv,8,64);
      sq += __shfl_xor(sq,1,64); sq += __shfl_xor(sq,2,64);
      sq += __shfl_xor(sq,4,64); sq += __shfl_xor(sq,8,64);
      float m = sv*(1.f/64.f);
      float var = sq*(1.f/64.f) - m*m;
      float rs = rsqrtf(var + 1e-5f);
      size_t tok = (size_t)t0 + (wv*2+mi)*16 + q*4 + r;
      #pragma unroll
      for (int o = 0; o < 4; ++o){
        float wn = (v[o]-m)*rs*gnw[o] + gnb[o];
        wn = nan2num(wn, 0.5f, 1.f, 0.f);
        wn = 1.f/(1.f + __expf(-wn));
        wn = fminf(fmaxf(wn, 0.01f), 0.99f);
        wg[tok*64 + o*16 + n] = wn;
      }
    }
  }
}

// ================================================================ G2: conv + xproj
__global__ __launch_bounds__(256) void g2_convproj(
    const float* __restrict__ xa, const float* __restrict__ xe,
    const float* __restrict__ cwf, const float* __restrict__ cbf,
    const float* __restrict__ cwr, const float* __restrict__ cbr,
    const float* __restrict__ xpwf, const float* __restrict__ xpwr,
    float* __restrict__ uf, float* __restrict__ ur,
    float* __restrict__ dltf, float* __restrict__ dltr,
    float* __restrict__ Bf, float* __restrict__ Cf,
    float* __restrict__ Br, float* __restrict__ Cr)
{
  __shared__ __align__(16) short Wl[2*48*72];
  __shared__ __align__(16) short Al[2*128*72];
  int tid = threadIdx.x;
  int b = blockIdx.x >> 7, l0 = (blockIdx.x & 127) * 128;
  size_t base = (size_t)b * SEQL;
  for (int sseg = tid; sseg < 2*48*8; sseg += 256){
    int s = sseg >= 48*8;
    int rs = sseg - s*48*8;
    int row = rs >> 3, sg = rs & 7;
    const float* xp = s ? xpwr : xpwf;
    short8 v = {0,0,0,0,0,0,0,0};
    int srcrow = (row < 32) ? (4+row) : (row < 36) ? (row-32) : -1;
    if (srcrow >= 0){
      const float* src = xp + (size_t)srcrow*64 + sg*8;
      float4 f0 = ((const float4*)src)[0];
      float4 f1 = ((const float4*)src)[1];
      v[0]=(short)f2b(f0.x); v[1]=(short)f2b(f0.y); v[2]=(short)f2b(f0.z); v[3]=(short)f2b(f0.w);
      v[4]=(short)f2b(f1.x); v[5]=(short)f2b(f1.y); v[6]=(short)f2b(f1.z); v[7]=(short)f2b(f1.w);
    }
    *(short8*)&Wl[(s*48+row)*72 + sg*8] = v;
  }
  {
    int d = tid & 63, lq = tid >> 6;
    float4 wf4 = ((const float4*)cwf)[d];
    float4 wr4 = ((const float4*)cwr)[d];
    float bf = cbf[d], brr = cbr[d];
    for (int i = 0; i < 8; ++i){
      int ll = i*16 + lq*4;
      int gl = l0 + ll;
      float rv[7], sv[7];
      #pragma unroll
      for (int j = 0; j < 7; ++j){
        int li = gl - 3 + j;
        rv[j] = (li >= 0) ? xa[(base + li)*64 + d] : 0.f;
        int lj = gl + j;
        sv[j] = (lj < SEQL) ? xe[(base + lj)*64 + d] : 0.f;
      }
      #pragma unroll
      for (int k = 0; k < 4; ++k){
        float a = bf + wf4.x*rv[k] + wf4.y*rv[k+1] + wf4.z*rv[k+2] + wf4.w*rv[k+3];
        a = siluf(a);
        uf[(base + gl + k)*64 + d] = a;
        Al[(ll+k)*72 + d] = (short)f2b(a);
        float r = brr + wr4.w*sv[k] + wr4.z*sv[k+1] + wr4.y*sv[k+2] + wr4.x*sv[k+3];
        r = siluf(r);
        ur[(base + gl + k)*64 + d] = r;
        Al[(128 + ll + k)*72 + d] = (short)f2b(r);
      }
    }
  }
  __syncthreads();
  int lane = tid & 63, wv = tid >> 6;
  int n = lane & 15, q = lane >> 4;
  #pragma unroll
  for (int s = 0; s < 2; ++s){
    const short* As = &Al[s*128*72];
    const short* Ws = &Wl[s*48*72];
    float* Bo = s ? Br : Bf;
    float* Co = s ? Cr : Cf;
    float* Do = s ? dltr : dltf;
    #pragma unroll
    for (int mi = 0; mi < 2; ++mi){
      int mt = wv*2 + mi;
      short8 a0 = *(const short8*)&As[(mt*16 + n)*72 + q*8];
      short8 a1 = *(const short8*)&As[(mt*16 + n)*72 + 32 + q*8];
      f32x4 acc[3];
      #pragma unroll
      for (int o = 0; o < 3; ++o){
        short8 b0 = *(const short8*)&Ws[(o*16 + n)*72 + q*8];
        short8 b1 = *(const short8*)&Ws[(o*16 + n)*72 + 32 + q*8];
        f32x4 c = {0.f, 0.f, 0.f, 0.f};
        c = __builtin_amdgcn_mfma_f32_16x16x32_bf16(a0, b0, c, 0, 0, 0);
        c = __builtin_amdgcn_mfma_f32_16x16x32_bf16(a1, b1, c, 0, 0, 0);
        acc[o] = c;
      }
      #pragma unroll
      for (int r = 0; r < 4; ++r){
        size_t tok = base + l0 + mt*16 + q*4 + r;
        Bo[tok*16 + n] = acc[0][r];
        Co[tok*16 + n] = acc[1][r];
        if (n < 4) Do[tok*4 + n] = acc[2][r];
      }
    }
  }
}

// ================================================================ K4a: chunk compose (lean LDS)
// block per (b,dir,chunk); thread = (d = wv*16+(lane&15), nq = lane>>4), 4 states.
// LDS = u (16K) + B (4K) + dlt (1K) = 21 KB; dt recomputed inline per thread.
__global__ __launch_bounds__(256) void k4a_scanA(
    const float* __restrict__ dltf, const float* __restrict__ dltr,
    const float* __restrict__ dtwf, const float* __restrict__ dtbf,
    const float* __restrict__ dtwr, const float* __restrict__ dtbr,
    const float* __restrict__ uf,  const float* __restrict__ ur,
    const float* __restrict__ Bf,  const float* __restrict__ Br,
    const float* __restrict__ Alf, const float* __restrict__ Alr,
    float* __restrict__ P, float* __restrict__ S)
{
  __shared__ float sU[64*64];
  __shared__ float sB[64*16];
  __shared__ float4 sDlt[64];
  int tid = threadIdx.x;
  int bx = blockIdx.x;
  int c = bx & (NCH-1), dir = (bx >> 8) & 1, b = bx >> 9;
  const float* dlt = dir ? dltr : dltf;
  const float* u   = dir ? ur  : uf;
  const float* Bm  = dir ? Br  : Bf;
  const float* Al  = dir ? Alr : Alf;
  const float* dtw = dir ? dtwr : dtwf;
  const float* dtb = dir ? dtbr : dtbf;
  size_t t0 = (size_t)b*SEQL + (dir ? (SEQL - (size_t)(c+1)*CHL) : (size_t)c*CHL);
  {
    const float4* gu = (const float4*)(u + t0*64);
    #pragma unroll
    for (int i = 0; i < 4; ++i)
      ((float4*)sU)[tid + i*256] = gu[tid + i*256];
    ((float4*)sB)[tid] = ((const float4*)(Bm + t0*16))[tid];
    if (tid < 64) sDlt[tid] = ((const float4*)(dlt + t0*4))[tid];
  }
  __syncthreads();
  int lane = tid & 63, wv = tid >> 6;
  int nq = lane >> 4;
  int d = wv*16 + (lane & 15);
  float4 wd = ((const float4*)dtw)[d];
  float bd = dtb[d];
  float A2[4], Pp[4] = {1.f,1.f,1.f,1.f}, Ss[4] = {0.f,0.f,0.f,0.f};
  #pragma unroll
  for (int j = 0; j < 4; ++j)
    A2[j] = -__expf(Al[d*16 + nq*4 + j]) * 1.44269504f;
  #pragma unroll 4
  for (int i = 0; i < CHL; ++i){
    int li = dir ? (CHL-1-i) : i;
    float4 dl = sDlt[li];
    float dtv = softplus_fast(fmaf(wd.x,dl.x, fmaf(wd.y,dl.y,
                              fmaf(wd.z,dl.z, fmaf(wd.w,dl.w, bd)))));
    float uv  = sU[li*64 + d];
    float du  = dtv * uv;
    float4 b4 = *(const float4*)&sB[li*16 + nq*4];
    float bb[4] = {b4.x, b4.y, b4.z, b4.w};
    #pragma unroll
    for (int j = 0; j < 4; ++j){
      float a = exp2f(dtv*A2[j]);
      Pp[j] *= a;
      Ss[j] = fmaf(a, Ss[j], du*bb[j]);
    }
  }
  size_t pidx = (((size_t)(b*2+dir)*NCH + c)*64 + d)*16 + nq*4;
  *(float4*)(P + pidx) = make_float4(Pp[0],Pp[1],Pp[2],Pp[3]);
  *(float4*)(S + pidx) = make_float4(Ss[0],Ss[1],Ss[2],Ss[3]);
}

// ================================================================ K4b: Kogge-Stone carry scan
__global__ __launch_bounds__(256) void k4b_ks(float* __restrict__ P,
                                              const float* __restrict__ S)
{
  __shared__ float Pl[256*18], Sl[256*18];
  int c = threadIdx.x;
  int d = blockIdx.x & 63, bd = blockIdx.x >> 6;
  size_t idx = (((size_t)bd*NCH + c)*64 + d)*16;
  float p[16], s[16];
  #pragma unroll
  for (int k = 0; k < 4; k++){
    float4 pv = ((const float4*)(P + idx))[k];
    float4 sv = ((const float4*)(S + idx))[k];
    p[4*k]=pv.x; p[4*k+1]=pv.y; p[4*k+2]=pv.z; p[4*k+3]=pv.w;
    s[4*k]=sv.x; s[4*k+1]=sv.y; s[4*k+2]=sv.z; s[4*k+3]=sv.w;
  }
  #pragma unroll
  for (int j = 0; j < 8; j++){
    *(float2*)&Pl[c*18 + 2*j] = make_float2(p[2*j], p[2*j+1]);
    *(float2*)&Sl[c*18 + 2*j] = make_float2(s[2*j], s[2*j+1]);
  }
  for (int step = 1; step < NCH; step <<= 1){
    __syncthreads();
    float pp[16], ss[16];
    bool act = (c >= step);
    if (act){
      #pragma unroll
      for (int j = 0; j < 8; j++){
        float2 tp = *(const float2*)&Pl[(c-step)*18 + 2*j];
        float2 ts = *(const float2*)&Sl[(c-step)*18 + 2*j];
        pp[2*j]=tp.x; pp[2*j+1]=tp.y; ss[2*j]=ts.x; ss[2*j+1]=ts.y;
      }
    }
    __syncthreads();
    if (act){
      #pragma unroll
      for (int n = 0; n < 16; n++){
        s[n] = fmaf(p[n], ss[n], s[n]);
        p[n] *= pp[n];
      }
      #pragma unroll
      for (int j = 0; j < 8; j++){
        *(float2*)&Pl[c*18 + 2*j] = make_float2(p[2*j], p[2*j+1]);
        *(float2*)&Sl[c*18 + 2*j] = make_float2(s[2*j], s[2*j+1]);
      }
    }
  }
  __syncthreads();
  float ho[16];
  if (c == 0){
    #pragma unroll
    for (int n = 0; n < 16; n++) ho[n] = 0.f;
  } else {
    #pragma unroll
    for (int j = 0; j < 8; j++){
      float2 ts = *(const float2*)&Sl[(c-1)*18 + 2*j];
      ho[2*j]=ts.x; ho[2*j+1]=ts.y;
    }
  }
  #pragma unroll
  for (int k = 0; k < 4; k++)
    ((float4*)(P + idx))[k] = make_float4(ho[4*k], ho[4*k+1], ho[4*k+2], ho[4*k+3]);
}

// ================================================================ K4c: scan pass B (lean LDS)
// LDS = u (16K) + B (4K) + C (4K) + dlt (1K) = 25 KB; dt inline; y stored direct;
// shfl reduce batched by 4 iterations to amortize ds_permute latency.
__global__ __launch_bounds__(256) void k4c_scanB(
    const float* __restrict__ dltf, const float* __restrict__ dltr,
    const float* __restrict__ dtwf, const float* __restrict__ dtbf,
    const float* __restrict__ dtwr, const float* __restrict__ dtbr,
    const float* __restrict__ uf,  const float* __restrict__ ur,
    const float* __restrict__ Bf,  const float* __restrict__ Br,
    const float* __restrict__ Cf,  const float* __restrict__ Cr,
    const float* __restrict__ Alf, const float* __restrict__ Alr,
    const float* __restrict__ Dvf, const float* __restrict__ Dvr,
    const float* __restrict__ Hpre, float* __restrict__ yf, float* __restrict__ yr)
{
  __shared__ float sU[64*64];
  __shared__ float sB[64*16];
  __shared__ float sC[64*16];
  __shared__ float4 sDlt[64];
  int tid = threadIdx.x;
  int bx = blockIdx.x;
  int c = bx & (NCH-1), dir = (bx >> 8) & 1, b = bx >> 9;
  const float* dlt = dir ? dltr : dltf;
  const float* u   = dir ? ur  : uf;
  const float* Bm  = dir ? Br  : Bf;
  const float* Cm  = dir ? Cr  : Cf;
  const float* Al  = dir ? Alr : Alf;
  const float* dtw = dir ? dtwr : dtwf;
  const float* dtb = dir ? dtbr : dtbf;
  const float* Dv  = dir ? Dvr : Dvf;
  float* y = dir ? yr : yf;
  size_t t0 = (size_t)b*SEQL + (dir ? (SEQL - (size_t)(c+1)*CHL) : (size_t)c*CHL);
  {
    const float4* gu = (const float4*)(u + t0*64);
    #pragma unroll
    for (int i = 0; i < 4; ++i)
      ((float4*)sU)[tid + i*256] = gu[tid + i*256];
    ((float4*)sB)[tid] = ((const float4*)(Bm + t0*16))[tid];
    ((float4*)sC)[tid] = ((const float4*)(Cm + t0*16))[tid];
    if (tid < 64) sDlt[tid] = ((const float4*)(dlt + t0*4))[tid];
  }
  __syncthreads();
  int lane = tid & 63, wv = tid >> 6;
  int nq = lane >> 4;
  int d = wv*16 + (lane & 15);
  float4 wd = ((const float4*)dtw)[d];
  float bd = dtb[d];
  float Dd = Dv[d];
  float A2[4], h[4];
  #pragma unroll
  for (int j = 0; j < 4; ++j)
    A2[j] = -__expf(Al[d*16 + nq*4 + j]) * 1.44269504f;
  size_t pidx = (((size_t)(b*2+dir)*NCH + c)*64 + d)*16 + nq*4;
  float4 h4 = *(const float4*)(Hpre + pidx);
  h[0]=h4.x; h[1]=h4.y; h[2]=h4.z; h[3]=h4.w;
  for (int i = 0; i < CHL; i += 4){
    float yvk[4];
    #pragma unroll
    for (int k = 0; k < 4; ++k){
      int li = dir ? (CHL-1-(i+k)) : (i+k);
      float4 dl = sDlt[li];
      float dtv = softplus_fast(fmaf(wd.x,dl.x, fmaf(wd.y,dl.y,
                                fmaf(wd.z,dl.z, fmaf(wd.w,dl.w, bd)))));
      float uv  = sU[li*64 + d];
      float du  = dtv * uv;
      float4 b4 = *(const float4*)&sB[li*16 + nq*4];
      float4 c4 = *(const float4*)&sC[li*16 + nq*4];
      float bb[4] = {b4.x, b4.y, b4.z, b4.w};
      float cc[4] = {c4.x, c4.y, c4.z, c4.w};
      float yv = nq ? 0.f : uv*Dd;
      #pragma unroll
      for (int j = 0; j < 4; ++j){
        float a = exp2f(dtv*A2[j]);
        h[j] = fmaf(a, h[j], du*bb[j]);
        yv = fmaf(h[j], cc[j], yv);
      }
      yvk[k] = yv;
    }
    #pragma unroll
    for (int k = 0; k < 4; ++k){
      yvk[k] += __shfl_xor(yvk[k], 16, 64);
      yvk[k] += __shfl_xor(yvk[k], 32, 64);
    }
    if (nq == 0){
      #pragma unroll
      for (int k = 0; k < 4; ++k){
        int li = dir ? (CHL-1-(i+k)) : (i+k);
        y[(t0 + li)*64 + d] = yvk[k];
      }
    }
  }
}

// ================================================================ G3: epilogue
__global__ __launch_bounds__(256) void g3_post(
    const float* __restrict__ yf, const float* __restrict__ yr,
    const unsigned short* __restrict__ zb, const unsigned short* __restrict__ zeb,
    const float* __restrict__ wg, const float* __restrict__ x0n,
    const float* __restrict__ in0,
    const float* __restrict__ mnw, const float* __restrict__ opw,
    const float* __restrict__ pnw, const float* __restrict__ pnb,
    float* __restrict__ out)
{
  __shared__ __align__(16) short Wl[64*72];
  __shared__ __align__(16) short Al[64*72];
  __shared__ float Dbuf[64*66];
  int tid = threadIdx.x;
  int t0 = blockIdx.x * 64;
  for (int sseg = tid; sseg < 64*8; sseg += 256){
    int row = sseg >> 3, sg = sseg & 7;
    const float* src = opw + (size_t)row*64 + sg*8;
    float4 f0 = ((const float4*)src)[0];
    float4 f1 = ((const float4*)src)[1];
    short8 v;
    v[0]=(short)f2b(f0.x); v[1]=(short)f2b(f0.y); v[2]=(short)f2b(f0.z); v[3]=(short)f2b(f0.w);
    v[4]=(short)f2b(f1.x); v[5]=(short)f2b(f1.y); v[6]=(short)f2b(f1.z); v[7]=(short)f2b(f1.w);
    *(short8*)&Wl[row*72 + sg*8] = v;
  }
  {
    int tl = tid >> 2, p = tid & 3;
    size_t g = (size_t)(t0 + tl)*64 + p*16;
    float4 yf4[4], yr4[4];
    #pragma unroll
    for (int i = 0; i < 4; i++){
      yf4[i] = ((const float4*)(yf + g))[i];
      yr4[i] = ((const float4*)(yr + g))[i];
    }
    short8 z8a  = *(const short8*)(zb + g);
    short8 z8b  = *(const short8*)(zb + g + 8);
    short8 ze8a = *(const short8*)(zeb + g);
    short8 ze8b = *(const short8*)(zeb + g + 8);
    float vy[16]; float ss = 0.f;
    #pragma unroll
    for (int i = 0; i < 16; i++){
      float yfv = ((const float*)yf4)[i];
      float yrv = ((const float*)yr4)[i];
      float zv  = b2f((unsigned short)(i < 8 ? z8a[i] : z8b[i-8]));
      float zev = b2f((unsigned short)(i < 8 ? ze8a[i] : ze8b[i-8]));
      float v = 0.5f*(yfv*siluf(zv) + yrv*siluf(zev));
      vy[i] = v; ss += v*v;
    }
    ss += __shfl_xor(ss, 1, 64);
    ss += __shfl_xor(ss, 2, 64);
    float rms = rsqrtf(ss*(1.f/64.f) + 1e-5f);
    #pragma unroll
    for (int i = 0; i < 16; i++){
      float w = mnw[p*16 + i];
      Al[tl*72 + p*16 + i] = (short)f2b(vy[i]*rms*w);
    }
  }
  __syncthreads();
  int lane = tid & 63, wv = tid >> 6;
  int n = lane & 15, q = lane >> 4;
  {
    short8 a0 = *(const short8*)&Al[(wv*16 + n)*72 + q*8];
    short8 a1 = *(const short8*)&Al[(wv*16 + n)*72 + 32 + q*8];
    #pragma unroll
    for (int o = 0; o < 4; ++o){
      short8 b0 = *(const short8*)&Wl[(o*16 + n)*72 + q*8];
      short8 b1 = *(const short8*)&Wl[(o*16 + n)*72 + 32 + q*8];
      f32x4 c = {0.f, 0.f, 0.f, 0.f};
      c = __builtin_amdgcn_mfma_f32_16x16x32_bf16(a0, b0, c, 0, 0, 0);
      c = __builtin_amdgcn_mfma_f32_16x16x32_bf16(a1, b1, c, 0, 0, 0);
      #pragma unroll
      for (int r = 0; r < 4; ++r)
        Dbuf[(wv*16 + q*4 + r)*66 + o*16 + n] = c[r];
    }
  }
  __syncthreads();
  float gpw = pnw[lane], gpb = pnb[lane];
  float s1, s2;
  for (int i = 0; i < 16; ++i){
    int tl = wv*16 + i;
    size_t off = (size_t)(t0 + tl)*64 + lane;
    float v = Dbuf[tl*66 + lane];
    s1 = v; s2 = v*v;
    #pragma unroll
    for (int o2 = 32; o2 > 0; o2 >>= 1){ s1 += __shfl_xor(s1,o2,64); s2 += __shfl_xor(s2,o2,64); }
    float m = s1*(1.f/64.f);
    float qv = s2*(1.f/64.f) - m*m;
    float o = (v-m)*rsqrtf(qv+1e-5f)*gpw + gpb;
    o = nan2num(o, 0.f, 1.f, -1.f);
    float w = wg[off];
    float skip = nan2num(in0[off], 0.f, 1.f, -1.f);
    out[off] = fmaf(o, w, fmaf(x0n[off], 1.f - w, skip));
  }
}

// ================================================================ launcher
extern "C" void kernel_launch(void* const* d_in, const int* in_sizes, int n_in,
                              void* d_out, int out_size, void* d_ws, size_t ws_size,
                              hipStream_t stream)
{
  (void)in_sizes; (void)n_in; (void)out_size; (void)ws_size;
  const float* in0  = (const float*)d_in[0];
  const float* in1  = (const float*)d_in[1];
  const float* n0w  = (const float*)d_in[2];
  const float* n0b  = (const float*)d_in[3];
  const float* n1w  = (const float*)d_in[4];
  const float* n1b  = (const float*)d_in[5];
  const float* cww  = (const float*)d_in[6];
  const float* cwb  = (const float*)d_in[7];
  const float* cwnw = (const float*)d_in[8];
  const float* cwnb = (const float*)d_in[9];
  const float* ipw  = (const float*)d_in[10];
  const float* ipew = (const float*)d_in[11];
  const float* cwf  = (const float*)d_in[12];
  const float* cbf  = (const float*)d_in[13];
  const float* xpwf = (const float*)d_in[14];
  const float* dtwf = (const float*)d_in[15];
  const float* dtbf = (const float*)d_in[16];
  const float* Alf  = (const float*)d_in[17];
  const float* Dvf  = (const float*)d_in[18];
  const float* cwr  = (const float*)d_in[19];
  const float* cbr  = (const float*)d_in[20];
  const float* xpwr = (const float*)d_in[21];
  const float* dtwr = (const float*)d_in[22];
  const float* dtbr = (const float*)d_in[23];
  const float* Alr  = (const float*)d_in[24];
  const float* Dvr  = (const float*)d_in[25];
  const float* mnw  = (const float*)d_in[26];
  const float* opw  = (const float*)d_in[27];
  const float* pnw  = (const float*)d_in[28];
  const float* pnb  = (const float*)d_in[29];

  float* ws  = (float*)d_ws;
  float* x0n = ws + 0*EL;
  float* xa  = ws + 1*EL;   // conv input fwd; reused as yf
  float* xe  = ws + 2*EL;   // conv input rev; reused as yr
  float* uf  = ws + 3*EL;
  float* ur  = ws + 4*EL;
  float* wg  = ws + 5*EL;
  float* Bf  = ws + 6*EL;              // TOK*16 each (4 arrays = EL total)
  float* Cf  = Bf + (size_t)TOK*16;
  float* Br  = Cf + (size_t)TOK*16;
  float* Cr  = Br + (size_t)TOK*16;
  float* P   = ws + 7*EL;              // 2*TOK*16 floats = EL/2
  float* S   = P + 2*(size_t)TOK*16;   // EL/2
  unsigned short* zb  = (unsigned short*)(ws + 8*EL);
  unsigned short* zeb = zb + EL;
  float* dltf = ws + 9*EL;             // TOK*4 each
  float* dltr = dltf + (size_t)TOK*4;
  float* yfp = xa;
  float* yrp = xe;

  mega1<<<512, 256, 0, stream>>>(in0, in1, n0w, n0b, n1w, n1b, cww, cwb,
                                 cwnw, cwnb, ipw, ipew,
                                 x0n, wg, xa, xe, zb, zeb);
  g2_convproj<<<512, 256, 0, stream>>>(xa, xe, cwf, cbf, cwr, cbr,
                                       xpwf, xpwr,
                                       uf, ur, dltf, dltr, Bf, Cf, Br, Cr);
  k4a_scanA<<<2048, 256, 0, stream>>>(dltf, dltr, dtwf, dtbf, dtwr, dtbr,
                                      uf, ur, Bf, Br, Alf, Alr, P, S);
  k4b_ks<<<512, 256, 0, stream>>>(P, S);
  k4c_scanB<<<2048, 256, 0, stream>>>(dltf, dltr, dtwf, dtbf, dtwr, dtbr,
                                      uf, ur, Bf, Br, Cf, Cr,
                                      Alf, Alr, Dvf, Dvr, P, yfp, yrp);
  g3_post<<<1024, 256, 0, stream>>>(yfp, yrp, zb, zeb, wg, x0n, in0,
                                    mnw, opw, pnw, pnb, (float*)d_out);
}